// Round 1
// baseline (1392.832 us; speedup 1.0000x reference)
//
#include <hip/hip_runtime.h>

#define B 8
#define N 1024
#define D_IN 64
#define H 128
#define HEADS 4
#define HD 32
#define L 2
#define EPS 1e-5f
#define NEG_BIG -1e30f

// ---------------- encoder: h = relu(x @ enc_w.T + enc_b) ----------------
__global__ __launch_bounds__(H) void enc_kernel(
    const float* __restrict__ x, const float* __restrict__ w,
    const float* __restrict__ b, float* __restrict__ h) {
    __shared__ float xs[D_IN];
    int row = blockIdx.x;          // 0 .. B*N-1
    int c = threadIdx.x;           // 0 .. 127
    if (c < D_IN) xs[c] = x[(size_t)row * D_IN + c];
    __syncthreads();
    float acc = b[c];
    const float* wr = w + (size_t)c * D_IN;
    #pragma unroll 8
    for (int kk = 0; kk < D_IN; ++kk) acc += xs[kk] * wr[kk];
    h[(size_t)row * H + c] = fmaxf(acc, 0.0f);
}

// ---------------- fused q/k/v projection ----------------
__global__ __launch_bounds__(H) void qkv_kernel(
    const float* __restrict__ h,
    const float* __restrict__ qw, const float* __restrict__ qb,
    const float* __restrict__ kw, const float* __restrict__ kb,
    const float* __restrict__ vw, const float* __restrict__ vb,
    float* __restrict__ q, float* __restrict__ k, float* __restrict__ v) {
    __shared__ float hs[H];
    int row = blockIdx.x;
    int c = threadIdx.x;
    hs[c] = h[(size_t)row * H + c];
    __syncthreads();
    float aq = qb[c], ak = kb[c], av = vb[c];
    const float* qwr = qw + (size_t)c * H;
    const float* kwr = kw + (size_t)c * H;
    const float* vwr = vw + (size_t)c * H;
    #pragma unroll 8
    for (int kk = 0; kk < H; ++kk) {
        float hv = hs[kk];
        aq += hv * qwr[kk];
        ak += hv * kwr[kk];
        av += hv * vwr[kk];
    }
    size_t o = (size_t)row * H + c;
    q[o] = aq; k[o] = ak; v[o] = av;
}

// ---------------- attention: one block per (b, head, i) row ----------------
__global__ __launch_bounds__(256) void attn_kernel(
    const float* __restrict__ q, const float* __restrict__ k,
    const float* __restrict__ v, const float* __restrict__ adj,
    float* __restrict__ out) {
    int bid = blockIdx.x;
    int i    = bid & (N - 1);
    int head = (bid >> 10) & (HEADS - 1);
    int b    = bid >> 12;
    int t = threadIdx.x;           // 0 .. 255

    __shared__ float qi[HD];
    __shared__ float sc[N];
    __shared__ float redm[4];
    __shared__ float reds[4];
    __shared__ float pv[8][HD];

    const float scale = 0.17677669529663687f;  // 32^-0.5

    if (t < HD) qi[t] = q[((size_t)(b * N + i) * HEADS + head) * HD + t] * scale;
    __syncthreads();

    const float* adjr = adj + ((size_t)b * N + i) * N;
    float lmax = NEG_BIG;
    for (int j = t; j < N; j += 256) {
        float s = NEG_BIG;
        if (adjr[j] != 0.0f) {
            const float* kr = k + ((size_t)(b * N + j) * HEADS + head) * HD;
            float acc = 0.0f;
            #pragma unroll
            for (int d = 0; d < HD; ++d) acc += qi[d] * kr[d];
            s = acc;
        }
        sc[j] = s;
        lmax = fmaxf(lmax, s);
    }
    #pragma unroll
    for (int off = 32; off; off >>= 1) lmax = fmaxf(lmax, __shfl_down(lmax, off));
    if ((t & 63) == 0) redm[t >> 6] = lmax;
    __syncthreads();
    float m = fmaxf(fmaxf(redm[0], redm[1]), fmaxf(redm[2], redm[3]));

    float lsum = 0.0f;
    for (int j = t; j < N; j += 256) {
        float s = sc[j];
        float e = (s < -0.9e30f) ? 0.0f : __expf(s - m);
        sc[j] = e;
        lsum += e;
    }
    #pragma unroll
    for (int off = 32; off; off >>= 1) lsum += __shfl_down(lsum, off);
    if ((t & 63) == 0) reds[t >> 6] = lsum;
    __syncthreads();
    float sum = reds[0] + reds[1] + reds[2] + reds[3];
    float inv = (sum > 0.0f) ? 1.0f / sum : 0.0f;

    // PV: thread t handles d = t&31, j-chunk = t>>5 (8 chunks of 128)
    int d = t & 31;
    int chunk = t >> 5;
    const float* vcol = v + (size_t)b * N * H + head * HD + d;
    float acc = 0.0f;
    int j0 = chunk * 128;
    for (int j = j0; j < j0 + 128; ++j) acc += sc[j] * vcol[(size_t)j * H];
    pv[chunk][d] = acc;
    __syncthreads();
    if (t < HD) {
        float o = 0.0f;
        #pragma unroll
        for (int c = 0; c < 8; ++c) o += pv[c][t];
        out[((size_t)(b * N + i)) * H + head * HD + t] = o * inv;
    }
}

// ------- output proj + layernorm + relu + residual (in-place h update) -------
__global__ __launch_bounds__(H) void oln_kernel(
    const float* __restrict__ ao, const float* __restrict__ ow,
    const float* __restrict__ ob, const float* __restrict__ g,
    const float* __restrict__ bb, float* __restrict__ h) {
    __shared__ float xs[H];
    __shared__ float r1[2], r2[2];
    int row = blockIdx.x;
    int c = threadIdx.x;           // 0 .. 127
    xs[c] = ao[(size_t)row * H + c];
    __syncthreads();
    float acc = ob[c];
    const float* wr = ow + (size_t)c * H;
    #pragma unroll 8
    for (int kk = 0; kk < H; ++kk) acc += xs[kk] * wr[kk];

    float s1 = acc, s2 = acc * acc;
    #pragma unroll
    for (int off = 32; off; off >>= 1) {
        s1 += __shfl_down(s1, off);
        s2 += __shfl_down(s2, off);
    }
    if ((c & 63) == 0) { r1[c >> 6] = s1; r2[c >> 6] = s2; }
    __syncthreads();
    float mu = (r1[0] + r1[1]) * (1.0f / H);
    float ms = (r2[0] + r2[1]) * (1.0f / H);
    float var = ms - mu * mu;
    float rs = rsqrtf(var + EPS);
    float y = (acc - mu) * rs * g[c] + bb[c];
    size_t o = (size_t)row * H + c;
    h[o] = fmaxf(y, 0.0f) + h[o];
}

// ---------------- final: out = h @ out_w.T + out_b ----------------
__global__ __launch_bounds__(H) void final_kernel(
    const float* __restrict__ h, const float* __restrict__ w,
    const float* __restrict__ b, float* __restrict__ out) {
    __shared__ float hs[H];
    int row = blockIdx.x;
    int c = threadIdx.x;
    hs[c] = h[(size_t)row * H + c];
    __syncthreads();
    float acc = b[c];
    const float* wr = w + (size_t)c * H;
    #pragma unroll 8
    for (int kk = 0; kk < H; ++kk) acc += hs[kk] * wr[kk];
    out[(size_t)row * H + c] = acc;
}

extern "C" void kernel_launch(void* const* d_in, const int* in_sizes, int n_in,
                              void* d_out, int out_size, void* d_ws, size_t ws_size,
                              hipStream_t stream) {
    const float* x     = (const float*)d_in[0];
    const float* adj   = (const float*)d_in[1];
    const float* enc_w = (const float*)d_in[2];
    const float* enc_b = (const float*)d_in[3];
    const float* q_w   = (const float*)d_in[4];
    const float* q_b   = (const float*)d_in[5];
    const float* k_w   = (const float*)d_in[6];
    const float* k_b   = (const float*)d_in[7];
    const float* v_w   = (const float*)d_in[8];
    const float* v_b   = (const float*)d_in[9];
    const float* o_w   = (const float*)d_in[10];
    const float* o_b   = (const float*)d_in[11];
    const float* ln_g  = (const float*)d_in[12];
    const float* ln_b  = (const float*)d_in[13];
    const float* out_w = (const float*)d_in[14];
    const float* out_b = (const float*)d_in[15];

    const size_t BNH = (size_t)B * N * H;
    float* h  = (float*)d_ws;
    float* q  = h + BNH;
    float* k  = q + BNH;
    float* v  = k + BNH;
    float* ao = v + BNH;

    enc_kernel<<<B * N, H, 0, stream>>>(x, enc_w, enc_b, h);
    for (int i = 0; i < L; ++i) {
        qkv_kernel<<<B * N, H, 0, stream>>>(
            h, q_w + (size_t)i * H * H, q_b + (size_t)i * H,
               k_w + (size_t)i * H * H, k_b + (size_t)i * H,
               v_w + (size_t)i * H * H, v_b + (size_t)i * H,
            q, k, v);
        attn_kernel<<<B * HEADS * N, 256, 0, stream>>>(q, k, v, adj, ao);
        oln_kernel<<<B * N, H, 0, stream>>>(
            ao, o_w + (size_t)i * H * H, o_b + (size_t)i * H,
            ln_g + (size_t)i * H, ln_b + (size_t)i * H, h);
    }
    final_kernel<<<B * N, H, 0, stream>>>(h, out_w, out_b, (float*)d_out);
}

// Round 3
// 393.716 us; speedup vs baseline: 3.5377x; 3.5377x over previous
//
#include <hip/hip_runtime.h>

#define B 8
#define N 1024
#define D_IN 64
#define H 128
#define HEADS 4
#define HD 32
#define L 2
#define EPS 1e-5f
#define NEG_BIG -1e30f

typedef __attribute__((ext_vector_type(8))) short bf16x8;
typedef __attribute__((ext_vector_type(4))) float f32x4;

__device__ __forceinline__ unsigned short f2bf(float f) {
    unsigned u = __float_as_uint(f);
    u = u + 0x7fffu + ((u >> 16) & 1u);
    return (unsigned short)(u >> 16);
}

__device__ __forceinline__ void gload_lds16(const void* g, void* l) {
    __builtin_amdgcn_global_load_lds(
        (const __attribute__((address_space(1))) unsigned int*)g,
        (__attribute__((address_space(3))) unsigned int*)l,
        16, 0, 0);
}

// ---------------- adj -> bitmask pack: word w covers 32 consecutive j ----------------
__global__ __launch_bounds__(256) void pack_kernel(
    const float* __restrict__ adj, unsigned* __restrict__ mb) {
    int wd = blockIdx.x * 256 + threadIdx.x;      // 0 .. B*N*N/32-1
    const float4* src = (const float4*)(adj + (size_t)wd * 32);
    unsigned m = 0;
    #pragma unroll
    for (int c = 0; c < 8; ++c) {
        float4 f = src[c];
        if (f.x != 0.0f) m |= 1u << (c * 4 + 0);
        if (f.y != 0.0f) m |= 1u << (c * 4 + 1);
        if (f.z != 0.0f) m |= 1u << (c * 4 + 2);
        if (f.w != 0.0f) m |= 1u << (c * 4 + 3);
    }
    mb[wd] = m;
}

// ---------------- encoder: h = relu(x @ enc_w.T + enc_b) ----------------
__global__ __launch_bounds__(H) void enc_kernel(
    const float* __restrict__ x, const float* __restrict__ w,
    const float* __restrict__ b, float* __restrict__ h) {
    __shared__ float xs[D_IN];
    int row = blockIdx.x;
    int c = threadIdx.x;
    if (c < D_IN) xs[c] = x[(size_t)row * D_IN + c];
    __syncthreads();
    float acc = b[c];
    const float* wr = w + (size_t)c * D_IN;
    #pragma unroll 8
    for (int kk = 0; kk < D_IN; ++kk) acc += xs[kk] * wr[kk];
    h[(size_t)row * H + c] = fmaxf(acc, 0.0f);
}

// ---------------- fused q/k/v projection, 8 rows/block, bf16 out ----------------
__global__ __launch_bounds__(256) void qkv_kernel(
    const float* __restrict__ h,
    const float* __restrict__ qw, const float* __restrict__ qb,
    const float* __restrict__ kw, const float* __restrict__ kb,
    const float* __restrict__ vw, const float* __restrict__ vb,
    unsigned short* __restrict__ q, unsigned short* __restrict__ k,
    unsigned short* __restrict__ v) {
    __shared__ float hs[8 * H];
    const int r0 = blockIdx.x * 8;
    const int t = threadIdx.x;
    const int c = t & 127;
    const int grp = t >> 7;

    ((float4*)hs)[t] = ((const float4*)(h + (size_t)r0 * H))[t];
    __syncthreads();

    float aq[4], ak[4], av[4];
    #pragma unroll
    for (int rr = 0; rr < 4; ++rr) { aq[rr] = qb[c]; ak[rr] = kb[c]; av[rr] = vb[c]; }

    const float4* qwr = (const float4*)(qw + (size_t)c * H);
    const float4* kwr = (const float4*)(kw + (size_t)c * H);
    const float4* vwr = (const float4*)(vw + (size_t)c * H);

    #pragma unroll 8
    for (int k4 = 0; k4 < 32; ++k4) {
        float4 wq = qwr[k4], wk = kwr[k4], wv = vwr[k4];
        #pragma unroll
        for (int rr = 0; rr < 4; ++rr) {
            float4 hv = ((const float4*)(hs + (grp * 4 + rr) * H))[k4];
            aq[rr] += hv.x * wq.x + hv.y * wq.y + hv.z * wq.z + hv.w * wq.w;
            ak[rr] += hv.x * wk.x + hv.y * wk.y + hv.z * wk.z + hv.w * wk.w;
            av[rr] += hv.x * wv.x + hv.y * wv.y + hv.z * wv.z + hv.w * wv.w;
        }
    }
    const float scale = 0.17677669529663687f;  // 32^-0.5 folded into q
    #pragma unroll
    for (int rr = 0; rr < 4; ++rr) {
        size_t o = (size_t)(r0 + grp * 4 + rr) * H + c;
        q[o] = f2bf(aq[rr] * scale);
        k[o] = f2bf(ak[rr]);
        v[o] = f2bf(av[rr]);
    }
}

// ---------------- MFMA flash attention: block = (b, head, 64 i-rows) ----------------
// Q/K tiles staged via global_load_lds with chunk XOR-swizzle (chunk ^= row&3),
// applied on the GLOBAL source (LDS stays linear) and undone on the ds_read side.
__global__ __launch_bounds__(256) void attn_kernel(
    const unsigned short* __restrict__ qg, const unsigned short* __restrict__ kg,
    const unsigned short* __restrict__ vg, const unsigned* __restrict__ mb,
    float* __restrict__ ao) {
    __shared__ unsigned short qt[64 * 32];      // Q tile, swizzled chunks
    __shared__ unsigned short kt[64 * 32];      // K tile, swizzled chunks
    __shared__ unsigned short vt[32 * 72];      // V^T tile, padded stride 72
    __shared__ unsigned short pl[4][16 * 72];   // per-wave P buffer, stride 72

    const int bid = blockIdx.x;
    const int itile = bid & 15;
    const int head = (bid >> 4) & 3;
    const int b = bid >> 6;
    const int i0 = itile * 64;

    const int t = threadIdx.x;
    const int w = t >> 6;
    const int lane = t & 63;
    const int g = lane >> 4;        // 0..3
    const int c16 = lane & 15;
    const int sw = c16 & 3;         // read-side swizzle key (row&3)

    const int srow = t >> 2;        // staging row 0..63
    const int sch = (t & 3) ^ ((t >> 2) & 3);   // swizzled source chunk

    // ---- stage Q (once), K/V/mask for jt=0 ----
    gload_lds16(qg + ((size_t)(b * N + i0 + srow)) * H + head * HD + sch * 8,
                (char*)qt + w * 1024);
    gload_lds16(kg + ((size_t)(b * N + srow)) * H + head * HD + sch * 8,
                (char*)kt + w * 1024);
    int4 vreg = *(const int4*)(vg + ((size_t)(b * N + srow)) * H + head * HD + (t & 3) * 8);

    const unsigned* mrow = mb + (size_t)(b * N + i0 + w * 16 + g * 4) * (N / 32);
    unsigned long long am[4];
    #pragma unroll
    for (int r = 0; r < 4; ++r)
        am[r] = *(const unsigned long long*)(mrow + (size_t)r * (N / 32));

    {
        union { int4 i4; unsigned short u[8]; } uv; uv.i4 = vreg;
        #pragma unroll
        for (int dd = 0; dd < 8; ++dd)
            vt[((t & 3) * 8 + dd) * 72 + srow] = uv.u[dd];
    }
    __syncthreads();

    const bf16x8 qfrag = *(const bf16x8*)(qt + (w * 16 + c16) * 32 + (g ^ sw) * 8);

    f32x4 oacc[2];
    oacc[0] = (f32x4){0.f, 0.f, 0.f, 0.f};
    oacc[1] = (f32x4){0.f, 0.f, 0.f, 0.f};
    float mrun[4], lrun[4];
    #pragma unroll
    for (int r = 0; r < 4; ++r) { mrun[r] = NEG_BIG; lrun[r] = 0.0f; }

    for (int jt = 0; jt < 16; ++jt) {
        // ---- S = Q K^T (4 col-subtiles of 16) ----
        f32x4 sacc[4];
        #pragma unroll
        for (int sub = 0; sub < 4; ++sub) {
            bf16x8 bfrag = *(const bf16x8*)(kt + (sub * 16 + c16) * 32 + (g ^ sw) * 8);
            f32x4 z = {0.f, 0.f, 0.f, 0.f};
            sacc[sub] = __builtin_amdgcn_mfma_f32_16x16x32_bf16(qfrag, bfrag, z, 0, 0, 0);
        }
        // ---- mask + online softmax (row = g*4+r, 16-lane group reduce) ----
        float pw[4][4], sf[4];
        #pragma unroll
        for (int r = 0; r < 4; ++r) {
            float sm[4];
            #pragma unroll
            for (int sub = 0; sub < 4; ++sub) {
                bool alive = (am[r] >> (sub * 16 + c16)) & 1ull;
                sm[sub] = alive ? sacc[sub][r] : NEG_BIG;
            }
            float mx = fmaxf(fmaxf(sm[0], sm[1]), fmaxf(sm[2], sm[3]));
            mx = fmaxf(mx, __shfl_xor(mx, 1));
            mx = fmaxf(mx, __shfl_xor(mx, 2));
            mx = fmaxf(mx, __shfl_xor(mx, 4));
            mx = fmaxf(mx, __shfl_xor(mx, 8));
            float mnew = fmaxf(mrun[r], mx);
            sf[r] = __expf(mrun[r] - mnew);
            mrun[r] = mnew;
            float rs = 0.f;
            #pragma unroll
            for (int sub = 0; sub < 4; ++sub) {
                float p = (sm[sub] > -0.9e30f) ? __expf(sm[sub] - mnew) : 0.0f;
                pw[sub][r] = p;
                rs += p;
            }
            rs += __shfl_xor(rs, 1);
            rs += __shfl_xor(rs, 2);
            rs += __shfl_xor(rs, 4);
            rs += __shfl_xor(rs, 8);
            lrun[r] = lrun[r] * sf[r] + rs;
        }
        // ---- write P (bf16) to per-wave LDS (row stride 72) ----
        #pragma unroll
        for (int r = 0; r < 4; ++r)
            #pragma unroll
            for (int sub = 0; sub < 4; ++sub)
                pl[w][(g * 4 + r) * 72 + sub * 16 + c16] = f2bf(pw[sub][r]);
        // rescale O while P writes land
        #pragma unroll
        for (int tt = 0; tt < 2; ++tt)
            #pragma unroll
            for (int r = 0; r < 4; ++r)
                oacc[tt][r] *= sf[r];
        asm volatile("s_waitcnt lgkmcnt(0)" ::: "memory");
        // ---- O += P V  (K=64: 2 k-steps; 2 d-subtiles) ----
        #pragma unroll
        for (int ks = 0; ks < 2; ++ks) {
            bf16x8 pa = *(const bf16x8*)(&pl[w][c16 * 72 + ks * 32 + g * 8]);
            #pragma unroll
            for (int tt = 0; tt < 2; ++tt) {
                bf16x8 vbf = *(const bf16x8*)(vt + (tt * 16 + c16) * 72 + ks * 32 + g * 8);
                oacc[tt] = __builtin_amdgcn_mfma_f32_16x16x32_bf16(pa, vbf, oacc[tt], 0, 0, 0);
            }
        }
        // ---- stage next tile ----
        if (jt < 15) {
            const int j0n = (jt + 1) * 64;
            __syncthreads();   // all waves done reading kt/vt
            gload_lds16(kg + ((size_t)(b * N + j0n + srow)) * H + head * HD + sch * 8,
                        (char*)kt + w * 1024);
            int4 vr = *(const int4*)(vg + ((size_t)(b * N + j0n + srow)) * H + head * HD + (t & 3) * 8);
            #pragma unroll
            for (int r = 0; r < 4; ++r)
                am[r] = *(const unsigned long long*)(mrow + (size_t)r * (N / 32) + (jt + 1) * 2);
            union { int4 i4; unsigned short u[8]; } uv2; uv2.i4 = vr;
            #pragma unroll
            for (int dd = 0; dd < 8; ++dd)
                vt[((t & 3) * 8 + dd) * 72 + srow] = uv2.u[dd];
            __syncthreads();   // staging visible
        }
    }
    // ---- epilogue: normalize (lsum==0 -> 0, matches nan_to_num) ----
    #pragma unroll
    for (int r = 0; r < 4; ++r) {
        float inv = (lrun[r] > 0.0f) ? (1.0f / lrun[r]) : 0.0f;
        int irow = i0 + w * 16 + g * 4 + r;
        #pragma unroll
        for (int tt = 0; tt < 2; ++tt)
            ao[((size_t)(b * N + irow)) * H + head * HD + tt * 16 + c16] = oacc[tt][r] * inv;
    }
}

// ------- output proj + layernorm + relu + residual (in-place h update) -------
__global__ __launch_bounds__(H) void oln_kernel(
    const float* __restrict__ ao, const float* __restrict__ ow,
    const float* __restrict__ ob, const float* __restrict__ g,
    const float* __restrict__ bb, float* __restrict__ h) {
    __shared__ float xs[H];
    __shared__ float r1[2], r2[2];
    int row = blockIdx.x;
    int c = threadIdx.x;
    xs[c] = ao[(size_t)row * H + c];
    __syncthreads();
    float acc = ob[c];
    const float* wr = ow + (size_t)c * H;
    #pragma unroll 8
    for (int kk = 0; kk < H; ++kk) acc += xs[kk] * wr[kk];

    float s1 = acc, s2 = acc * acc;
    #pragma unroll
    for (int off = 32; off; off >>= 1) {
        s1 += __shfl_down(s1, off);
        s2 += __shfl_down(s2, off);
    }
    if ((c & 63) == 0) { r1[c >> 6] = s1; r2[c >> 6] = s2; }
    __syncthreads();
    float mu = (r1[0] + r1[1]) * (1.0f / H);
    float ms = (r2[0] + r2[1]) * (1.0f / H);
    float var = ms - mu * mu;
    float rs = rsqrtf(var + EPS);
    float y = (acc - mu) * rs * g[c] + bb[c];
    size_t o = (size_t)row * H + c;
    h[o] = fmaxf(y, 0.0f) + h[o];
}

// ---------------- final: out = h @ out_w.T + out_b ----------------
__global__ __launch_bounds__(H) void final_kernel(
    const float* __restrict__ h, const float* __restrict__ w,
    const float* __restrict__ b, float* __restrict__ out) {
    __shared__ float hs[H];
    int row = blockIdx.x;
    int c = threadIdx.x;
    hs[c] = h[(size_t)row * H + c];
    __syncthreads();
    float acc = b[c];
    const float* wr = w + (size_t)c * H;
    #pragma unroll 8
    for (int kk = 0; kk < H; ++kk) acc += hs[kk] * wr[kk];
    out[(size_t)row * H + c] = acc;
}

extern "C" void kernel_launch(void* const* d_in, const int* in_sizes, int n_in,
                              void* d_out, int out_size, void* d_ws, size_t ws_size,
                              hipStream_t stream) {
    const float* x     = (const float*)d_in[0];
    const float* adj   = (const float*)d_in[1];
    const float* enc_w = (const float*)d_in[2];
    const float* enc_b = (const float*)d_in[3];
    const float* q_w   = (const float*)d_in[4];
    const float* q_b   = (const float*)d_in[5];
    const float* k_w   = (const float*)d_in[6];
    const float* k_b   = (const float*)d_in[7];
    const float* v_w   = (const float*)d_in[8];
    const float* v_b   = (const float*)d_in[9];
    const float* o_w   = (const float*)d_in[10];
    const float* o_b   = (const float*)d_in[11];
    const float* ln_g  = (const float*)d_in[12];
    const float* ln_b  = (const float*)d_in[13];
    const float* out_w = (const float*)d_in[14];
    const float* out_b = (const float*)d_in[15];

    const size_t BNH = (size_t)B * N * H;
    float* h  = (float*)d_ws;
    float* ao = h + BNH;
    unsigned short* qb = (unsigned short*)(ao + BNH);
    unsigned short* kb = qb + BNH;
    unsigned short* vb = kb + BNH;
    unsigned* mbits = (unsigned*)(vb + BNH);   // B*N*N/32 words = 1 MB

    pack_kernel<<<B * N * N / 32 / 256, 256, 0, stream>>>(adj, mbits);
    enc_kernel<<<B * N, H, 0, stream>>>(x, enc_w, enc_b, h);
    for (int i = 0; i < L; ++i) {
        qkv_kernel<<<B * N / 8, 256, 0, stream>>>(
            h, q_w + (size_t)i * H * H, q_b + (size_t)i * H,
               k_w + (size_t)i * H * H, k_b + (size_t)i * H,
               v_w + (size_t)i * H * H, v_b + (size_t)i * H,
            qb, kb, vb);
        attn_kernel<<<B * HEADS * (N / 64), 256, 0, stream>>>(qb, kb, vb, mbits, ao);
        oln_kernel<<<B * N, H, 0, stream>>>(
            ao, o_w + (size_t)i * H * H, o_b + (size_t)i * H,
            ln_g + (size_t)i * H, ln_b + (size_t)i * H, h);
    }
    final_kernel<<<B * N, H, 0, stream>>>(h, out_w, out_b, (float*)d_out);
}

// Round 4
// 140.364 us; speedup vs baseline: 9.9230x; 2.8050x over previous
//
#include <hip/hip_runtime.h>

#define B 8
#define N 1024
#define D_IN 64
#define H 128
#define HEADS 4
#define HD 32
#define L 2
#define EPS 1e-5f
#define NEG_BIG -1e30f
#define SCALE 0.17677669529663687f

typedef __attribute__((ext_vector_type(8))) short bf16x8;
typedef __attribute__((ext_vector_type(4))) float f32x4;

__device__ __forceinline__ unsigned short f2bf(float f) {
    unsigned u = __float_as_uint(f);
    u = u + 0x7fffu + ((u >> 16) & 1u);
    return (unsigned short)(u >> 16);
}
__device__ __forceinline__ float bf2f(unsigned short s) {
    return __uint_as_float(((unsigned)s) << 16);
}
__device__ __forceinline__ void gload_lds16(const void* g, void* l) {
    __builtin_amdgcn_global_load_lds(
        (const __attribute__((address_space(1))) unsigned int*)g,
        (__attribute__((address_space(3))) unsigned int*)l,
        16, 0, 0);
}

// ---------------- adj -> bitmask ----------------
__global__ __launch_bounds__(256) void pack_kernel(
    const float* __restrict__ adj, unsigned* __restrict__ mb) {
    int wd = blockIdx.x * 256 + threadIdx.x;
    const float4* src = (const float4*)(adj + (size_t)wd * 32);
    unsigned m = 0;
    #pragma unroll
    for (int c = 0; c < 8; ++c) {
        float4 f = src[c];
        if (f.x != 0.0f) m |= 1u << (c * 4 + 0);
        if (f.y != 0.0f) m |= 1u << (c * 4 + 1);
        if (f.z != 0.0f) m |= 1u << (c * 4 + 2);
        if (f.w != 0.0f) m |= 1u << (c * 4 + 3);
    }
    mb[wd] = m;
}

// ---------------- prep: bf16 conversions (x, enc_w, qkv weights+biases) ----------------
__global__ __launch_bounds__(256) void prep_kernel(
    const float* __restrict__ x, const float* __restrict__ enc_w,
    const float* __restrict__ q_w, const float* __restrict__ k_w,
    const float* __restrict__ v_w, const float* __restrict__ q_b,
    const float* __restrict__ k_b, const float* __restrict__ v_b,
    unsigned short* __restrict__ x_bf, unsigned short* __restrict__ wenc,
    unsigned short* __restrict__ wqkv, float* __restrict__ bqkv) {
    int id = blockIdx.x * 256 + threadIdx.x;
    const int XN = B * N * D_IN;
    const int WE = H * D_IN;
    const int WQ = L * 3 * H * H;
    const int BQ = L * 3 * H;
    if (id < XN) { x_bf[id] = f2bf(x[id]); return; }
    id -= XN;
    if (id < WE) { wenc[id] = f2bf(enc_w[id]); return; }
    id -= WE;
    if (id < WQ) {
        int layer = id / (3 * H * H);
        int r = id % (3 * H * H);
        int mat = r / (H * H);
        int e = r % (H * H);
        const float* src = mat == 0 ? q_w : (mat == 1 ? k_w : v_w);
        float f = src[layer * H * H + e];
        if (mat == 0) f *= SCALE;
        wqkv[id] = f2bf(f);
        return;
    }
    id -= WQ;
    if (id < BQ) {
        int layer = id / (3 * H);
        int r = id % (3 * H);
        int mat = r / H;
        int e = r % H;
        const float* src = mat == 0 ? q_b : (mat == 1 ? k_b : v_b);
        float f = src[layer * H + e];
        if (mat == 0) f *= SCALE;
        bqkv[id] = f;
    }
}

// ---------------- encoder MFMA: h = relu(x @ enc_w.T + b)  (K=64, NC=128) ----------------
__global__ __launch_bounds__(256) void enc_kernel(
    const unsigned short* __restrict__ x_bf, const unsigned short* __restrict__ wenc,
    const float* __restrict__ eb, float* __restrict__ h, unsigned short* __restrict__ h_bf) {
    __shared__ unsigned short wt[H * D_IN];
    __shared__ unsigned short at[64 * D_IN];
    const int t = threadIdx.x;
    const int r0 = blockIdx.x * 64;
    const int w = t >> 6, lane = t & 63, g = lane >> 4, c16 = lane & 15;

    #pragma unroll
    for (int i = 0; i < 4; ++i) {
        int ci = i * 256 + t, row = ci >> 3, cr = ci & 7;
        gload_lds16(wenc + row * 64 + (cr ^ (row & 7)) * 8, (char*)wt + (i * 4 + w) * 1024);
    }
    #pragma unroll
    for (int i = 0; i < 2; ++i) {
        int ci = i * 256 + t, row = ci >> 3, cr = ci & 7;
        gload_lds16(x_bf + (size_t)(r0 + row) * 64 + (cr ^ (row & 7)) * 8,
                    (char*)at + (i * 4 + w) * 1024);
    }
    __syncthreads();

    const int arow = w * 16 + c16;
    bf16x8 a0 = *(const bf16x8*)(at + arow * 64 + ((g ^ (arow & 7)) * 8));
    bf16x8 a1 = *(const bf16x8*)(at + arow * 64 + (((4 + g) ^ (arow & 7)) * 8));
    f32x4 acc[8];
    #pragma unroll
    for (int sub = 0; sub < 8; ++sub) {
        int bcol = sub * 16 + c16;
        bf16x8 b0 = *(const bf16x8*)(wt + bcol * 64 + ((g ^ (bcol & 7)) * 8));
        bf16x8 b1 = *(const bf16x8*)(wt + bcol * 64 + (((4 + g) ^ (bcol & 7)) * 8));
        f32x4 z = {0.f, 0.f, 0.f, 0.f};
        z = __builtin_amdgcn_mfma_f32_16x16x32_bf16(a0, b0, z, 0, 0, 0);
        acc[sub] = __builtin_amdgcn_mfma_f32_16x16x32_bf16(a1, b1, z, 0, 0, 0);
    }
    #pragma unroll
    for (int sub = 0; sub < 8; ++sub) {
        int col = sub * 16 + c16;
        float bias = eb[col];
        #pragma unroll
        for (int rr = 0; rr < 4; ++rr) {
            int row = r0 + w * 16 + g * 4 + rr;
            float v = fmaxf(acc[sub][rr] + bias, 0.0f);
            h[(size_t)row * H + col] = v;
            h_bf[(size_t)row * H + col] = f2bf(v);
        }
    }
}

// ---------------- fused q/k/v MFMA (K=128, NC=384) ----------------
__global__ __launch_bounds__(256) void qkv_kernel(
    const unsigned short* __restrict__ h_bf, const unsigned short* __restrict__ wqkv_l,
    const float* __restrict__ bqkv_l,
    unsigned short* __restrict__ q, unsigned short* __restrict__ k,
    unsigned short* __restrict__ v) {
    __shared__ unsigned short wt[384 * 128];   // 96 KB
    __shared__ unsigned short at[64 * 128];    // 16 KB
    const int t = threadIdx.x;
    const int r0 = blockIdx.x * 64;
    const int w = t >> 6, lane = t & 63, g = lane >> 4, c16 = lane & 15;

    #pragma unroll
    for (int i = 0; i < 24; ++i) {
        int ci = i * 256 + t, row = ci >> 4, cr = ci & 15;
        gload_lds16(wqkv_l + (size_t)row * 128 + (cr ^ (row & 7)) * 8,
                    (char*)wt + (i * 4 + w) * 1024);
    }
    #pragma unroll
    for (int i = 0; i < 4; ++i) {
        int ci = i * 256 + t, row = ci >> 4, cr = ci & 15;
        gload_lds16(h_bf + (size_t)(r0 + row) * 128 + (cr ^ (row & 7)) * 8,
                    (char*)at + (i * 4 + w) * 1024);
    }
    __syncthreads();

    const int arow = w * 16 + c16;
    bf16x8 a[4];
    #pragma unroll
    for (int ks = 0; ks < 4; ++ks)
        a[ks] = *(const bf16x8*)(at + arow * 128 + (((ks * 4 + g) ^ (arow & 7)) * 8));

    f32x4 acc[24];
    #pragma unroll
    for (int sub = 0; sub < 24; ++sub) {
        int bcol = sub * 16 + c16;
        f32x4 z = {0.f, 0.f, 0.f, 0.f};
        #pragma unroll
        for (int ks = 0; ks < 4; ++ks) {
            bf16x8 bb = *(const bf16x8*)(wt + (size_t)bcol * 128 + (((ks * 4 + g) ^ (bcol & 7)) * 8));
            z = __builtin_amdgcn_mfma_f32_16x16x32_bf16(a[ks], bb, z, 0, 0, 0);
        }
        acc[sub] = z;
    }
    #pragma unroll
    for (int sub = 0; sub < 24; ++sub) {
        int mat = sub >> 3;
        int col = (sub & 7) * 16 + c16;
        float bias = bqkv_l[mat * H + col];
        unsigned short* dst = mat == 0 ? q : (mat == 1 ? k : v);
        #pragma unroll
        for (int rr = 0; rr < 4; ++rr) {
            int row = r0 + w * 16 + g * 4 + rr;
            dst[(size_t)row * H + col] = f2bf(acc[sub][rr] + bias);
        }
    }
}

// ---------------- MFMA flash attention (unchanged from R3) ----------------
__global__ __launch_bounds__(256) void attn_kernel(
    const unsigned short* __restrict__ qg, const unsigned short* __restrict__ kg,
    const unsigned short* __restrict__ vg, const unsigned* __restrict__ mb,
    float* __restrict__ ao) {
    __shared__ unsigned short qt[64 * 32];
    __shared__ unsigned short kt[64 * 32];
    __shared__ unsigned short vt[32 * 72];
    __shared__ unsigned short pl[4][16 * 72];

    const int bid = blockIdx.x;
    const int itile = bid & 15;
    const int head = (bid >> 4) & 3;
    const int b = bid >> 6;
    const int i0 = itile * 64;

    const int t = threadIdx.x;
    const int w = t >> 6;
    const int lane = t & 63;
    const int g = lane >> 4;
    const int c16 = lane & 15;
    const int sw = c16 & 3;

    const int srow = t >> 2;
    const int sch = (t & 3) ^ ((t >> 2) & 3);

    gload_lds16(qg + ((size_t)(b * N + i0 + srow)) * H + head * HD + sch * 8,
                (char*)qt + w * 1024);
    gload_lds16(kg + ((size_t)(b * N + srow)) * H + head * HD + sch * 8,
                (char*)kt + w * 1024);
    int4 vreg = *(const int4*)(vg + ((size_t)(b * N + srow)) * H + head * HD + (t & 3) * 8);

    const unsigned* mrow = mb + (size_t)(b * N + i0 + w * 16 + g * 4) * (N / 32);
    unsigned long long am[4];
    #pragma unroll
    for (int r = 0; r < 4; ++r)
        am[r] = *(const unsigned long long*)(mrow + (size_t)r * (N / 32));

    {
        union { int4 i4; unsigned short u[8]; } uv; uv.i4 = vreg;
        #pragma unroll
        for (int dd = 0; dd < 8; ++dd)
            vt[((t & 3) * 8 + dd) * 72 + srow] = uv.u[dd];
    }
    __syncthreads();

    const bf16x8 qfrag = *(const bf16x8*)(qt + (w * 16 + c16) * 32 + (g ^ sw) * 8);

    f32x4 oacc[2];
    oacc[0] = (f32x4){0.f, 0.f, 0.f, 0.f};
    oacc[1] = (f32x4){0.f, 0.f, 0.f, 0.f};
    float mrun[4], lrun[4];
    #pragma unroll
    for (int r = 0; r < 4; ++r) { mrun[r] = NEG_BIG; lrun[r] = 0.0f; }

    for (int jt = 0; jt < 16; ++jt) {
        f32x4 sacc[4];
        #pragma unroll
        for (int sub = 0; sub < 4; ++sub) {
            bf16x8 bfrag = *(const bf16x8*)(kt + (sub * 16 + c16) * 32 + (g ^ sw) * 8);
            f32x4 z = {0.f, 0.f, 0.f, 0.f};
            sacc[sub] = __builtin_amdgcn_mfma_f32_16x16x32_bf16(qfrag, bfrag, z, 0, 0, 0);
        }
        float pw[4][4], sf[4];
        #pragma unroll
        for (int r = 0; r < 4; ++r) {
            float sm[4];
            #pragma unroll
            for (int sub = 0; sub < 4; ++sub) {
                bool alive = (am[r] >> (sub * 16 + c16)) & 1ull;
                sm[sub] = alive ? sacc[sub][r] : NEG_BIG;
            }
            float mx = fmaxf(fmaxf(sm[0], sm[1]), fmaxf(sm[2], sm[3]));
            mx = fmaxf(mx, __shfl_xor(mx, 1));
            mx = fmaxf(mx, __shfl_xor(mx, 2));
            mx = fmaxf(mx, __shfl_xor(mx, 4));
            mx = fmaxf(mx, __shfl_xor(mx, 8));
            float mnew = fmaxf(mrun[r], mx);
            sf[r] = __expf(mrun[r] - mnew);
            mrun[r] = mnew;
            float rs = 0.f;
            #pragma unroll
            for (int sub = 0; sub < 4; ++sub) {
                float p = (sm[sub] > -0.9e30f) ? __expf(sm[sub] - mnew) : 0.0f;
                pw[sub][r] = p;
                rs += p;
            }
            rs += __shfl_xor(rs, 1);
            rs += __shfl_xor(rs, 2);
            rs += __shfl_xor(rs, 4);
            rs += __shfl_xor(rs, 8);
            lrun[r] = lrun[r] * sf[r] + rs;
        }
        #pragma unroll
        for (int r = 0; r < 4; ++r)
            #pragma unroll
            for (int sub = 0; sub < 4; ++sub)
                pl[w][(g * 4 + r) * 72 + sub * 16 + c16] = f2bf(pw[sub][r]);
        #pragma unroll
        for (int tt = 0; tt < 2; ++tt)
            #pragma unroll
            for (int r = 0; r < 4; ++r)
                oacc[tt][r] *= sf[r];
        asm volatile("s_waitcnt lgkmcnt(0)" ::: "memory");
        #pragma unroll
        for (int ks = 0; ks < 2; ++ks) {
            bf16x8 pa = *(const bf16x8*)(&pl[w][c16 * 72 + ks * 32 + g * 8]);
            #pragma unroll
            for (int tt = 0; tt < 2; ++tt) {
                bf16x8 vbf = *(const bf16x8*)(vt + (tt * 16 + c16) * 72 + ks * 32 + g * 8);
                oacc[tt] = __builtin_amdgcn_mfma_f32_16x16x32_bf16(pa, vbf, oacc[tt], 0, 0, 0);
            }
        }
        if (jt < 15) {
            const int j0n = (jt + 1) * 64;
            __syncthreads();
            gload_lds16(kg + ((size_t)(b * N + j0n + srow)) * H + head * HD + sch * 8,
                        (char*)kt + w * 1024);
            int4 vr = *(const int4*)(vg + ((size_t)(b * N + j0n + srow)) * H + head * HD + (t & 3) * 8);
            #pragma unroll
            for (int r = 0; r < 4; ++r)
                am[r] = *(const unsigned long long*)(mrow + (size_t)r * (N / 32) + (jt + 1) * 2);
            union { int4 i4; unsigned short u[8]; } uv2; uv2.i4 = vr;
            #pragma unroll
            for (int dd = 0; dd < 8; ++dd)
                vt[((t & 3) * 8 + dd) * 72 + srow] = uv2.u[dd];
            __syncthreads();
        }
    }
    #pragma unroll
    for (int r = 0; r < 4; ++r) {
        float inv = (lrun[r] > 0.0f) ? (1.0f / lrun[r]) : 0.0f;
        int irow = i0 + w * 16 + g * 4 + r;
        #pragma unroll
        for (int tt = 0; tt < 2; ++tt)
            ao[((size_t)(b * N + irow)) * H + head * HD + tt * 16 + c16] = oacc[tt][r] * inv;
    }
}

// ---- split hi/lo staging helper: fp32 src tile -> bf16 hi/lo LDS (stride 130) ----
__device__ __forceinline__ void stage_split(
    const float* __restrict__ src, unsigned short* hi, unsigned short* lo,
    int nrows, int t) {
    int n4 = nrows * 32;   // float4s (128 cols / 4)
    for (int idx4 = t; idx4 < n4; idx4 += 256) {
        int row = idx4 >> 5, c4 = (idx4 & 31) * 4;
        float4 f = ((const float4*)src)[idx4];
        unsigned short h0 = f2bf(f.x), h1 = f2bf(f.y), h2 = f2bf(f.z), h3 = f2bf(f.w);
        unsigned short l0 = f2bf(f.x - bf2f(h0)), l1 = f2bf(f.y - bf2f(h1));
        unsigned short l2 = f2bf(f.z - bf2f(h2)), l3 = f2bf(f.w - bf2f(h3));
        *(unsigned*)(hi + row * 130 + c4)     = (unsigned)h0 | ((unsigned)h1 << 16);
        *(unsigned*)(hi + row * 130 + c4 + 2) = (unsigned)h2 | ((unsigned)h3 << 16);
        *(unsigned*)(lo + row * 130 + c4)     = (unsigned)l0 | ((unsigned)l1 << 16);
        *(unsigned*)(lo + row * 130 + c4 + 2) = (unsigned)l2 | ((unsigned)l3 << 16);
    }
}

// ------- O-proj + LN + relu + residual, 3-term split MFMA (K=128, NC=128) -------
__global__ __launch_bounds__(256) void oln_kernel(
    const float* __restrict__ ao, const float* __restrict__ ow,
    const float* __restrict__ ob, const float* __restrict__ lng,
    const float* __restrict__ lnb, float* __restrict__ h,
    unsigned short* __restrict__ h_bf) {
    __shared__ unsigned short ah[64 * 130], al[64 * 130];
    __shared__ unsigned short wh[128 * 130], wl[128 * 130];
    const int t = threadIdx.x;
    const int r0 = blockIdx.x * 64;
    const int w = t >> 6, lane = t & 63, g = lane >> 4, c16 = lane & 15;

    stage_split(ow, wh, wl, 128, t);
    stage_split(ao + (size_t)r0 * H, ah, al, 64, t);
    __syncthreads();

    const int arow = w * 16 + c16;
    bf16x8 ahf[4], alf[4];
    #pragma unroll
    for (int ks = 0; ks < 4; ++ks) {
        ahf[ks] = *(const bf16x8*)(ah + arow * 130 + ks * 32 + g * 8);
        alf[ks] = *(const bf16x8*)(al + arow * 130 + ks * 32 + g * 8);
    }
    f32x4 acc[8];
    #pragma unroll
    for (int sub = 0; sub < 8; ++sub) {
        int bcol = sub * 16 + c16;
        f32x4 z = {0.f, 0.f, 0.f, 0.f};
        #pragma unroll
        for (int ks = 0; ks < 4; ++ks) {
            bf16x8 bh = *(const bf16x8*)(wh + bcol * 130 + ks * 32 + g * 8);
            bf16x8 bl = *(const bf16x8*)(wl + bcol * 130 + ks * 32 + g * 8);
            z = __builtin_amdgcn_mfma_f32_16x16x32_bf16(ahf[ks], bh, z, 0, 0, 0);
            z = __builtin_amdgcn_mfma_f32_16x16x32_bf16(alf[ks], bh, z, 0, 0, 0);
            z = __builtin_amdgcn_mfma_f32_16x16x32_bf16(ahf[ks], bl, z, 0, 0, 0);
        }
        acc[sub] = z;
    }
    // bias + LN stats
    float val[8][4], s1[4] = {0, 0, 0, 0}, s2[4] = {0, 0, 0, 0};
    #pragma unroll
    for (int sub = 0; sub < 8; ++sub) {
        int col = sub * 16 + c16;
        float bias = ob[col];
        #pragma unroll
        for (int rr = 0; rr < 4; ++rr) {
            float vv = acc[sub][rr] + bias;
            val[sub][rr] = vv;
            s1[rr] += vv;
            s2[rr] += vv * vv;
        }
    }
    #pragma unroll
    for (int rr = 0; rr < 4; ++rr) {
        #pragma unroll
        for (int off = 1; off < 16; off <<= 1) {
            s1[rr] += __shfl_xor(s1[rr], off);
            s2[rr] += __shfl_xor(s2[rr], off);
        }
    }
    #pragma unroll
    for (int rr = 0; rr < 4; ++rr) {
        float mu = s1[rr] * (1.0f / H);
        float var = s2[rr] * (1.0f / H) - mu * mu;
        float rs = rsqrtf(var + EPS);
        int row = r0 + w * 16 + g * 4 + rr;
        #pragma unroll
        for (int sub = 0; sub < 8; ++sub) {
            int col = sub * 16 + c16;
            float y = (val[sub][rr] - mu) * rs * lng[col] + lnb[col];
            float hn = fmaxf(y, 0.0f) + h[(size_t)row * H + col];
            h[(size_t)row * H + col] = hn;
            h_bf[(size_t)row * H + col] = f2bf(hn);
        }
    }
}

// ------- final: out = h @ out_w.T + b, 3-term split MFMA -------
__global__ __launch_bounds__(256) void final_kernel(
    const float* __restrict__ h, const float* __restrict__ ow,
    const float* __restrict__ ob, float* __restrict__ out) {
    __shared__ unsigned short ah[64 * 130], al[64 * 130];
    __shared__ unsigned short wh[128 * 130], wl[128 * 130];
    const int t = threadIdx.x;
    const int r0 = blockIdx.x * 64;
    const int w = t >> 6, lane = t & 63, g = lane >> 4, c16 = lane & 15;

    stage_split(ow, wh, wl, 128, t);
    stage_split(h + (size_t)r0 * H, ah, al, 64, t);
    __syncthreads();

    const int arow = w * 16 + c16;
    bf16x8 ahf[4], alf[4];
    #pragma unroll
    for (int ks = 0; ks < 4; ++ks) {
        ahf[ks] = *(const bf16x8*)(ah + arow * 130 + ks * 32 + g * 8);
        alf[ks] = *(const bf16x8*)(al + arow * 130 + ks * 32 + g * 8);
    }
    #pragma unroll
    for (int sub = 0; sub < 8; ++sub) {
        int bcol = sub * 16 + c16;
        f32x4 z = {0.f, 0.f, 0.f, 0.f};
        #pragma unroll
        for (int ks = 0; ks < 4; ++ks) {
            bf16x8 bh = *(const bf16x8*)(wh + bcol * 130 + ks * 32 + g * 8);
            bf16x8 bl = *(const bf16x8*)(wl + bcol * 130 + ks * 32 + g * 8);
            z = __builtin_amdgcn_mfma_f32_16x16x32_bf16(ahf[ks], bh, z, 0, 0, 0);
            z = __builtin_amdgcn_mfma_f32_16x16x32_bf16(alf[ks], bh, z, 0, 0, 0);
            z = __builtin_amdgcn_mfma_f32_16x16x32_bf16(ahf[ks], bl, z, 0, 0, 0);
        }
        int col = sub * 16 + c16;
        float bias = ob[col];
        #pragma unroll
        for (int rr = 0; rr < 4; ++rr) {
            int row = r0 + w * 16 + g * 4 + rr;
            out[(size_t)row * H + col] = z[rr] + bias;
        }
    }
}

extern "C" void kernel_launch(void* const* d_in, const int* in_sizes, int n_in,
                              void* d_out, int out_size, void* d_ws, size_t ws_size,
                              hipStream_t stream) {
    const float* x     = (const float*)d_in[0];
    const float* adj   = (const float*)d_in[1];
    const float* enc_w = (const float*)d_in[2];
    const float* enc_b = (const float*)d_in[3];
    const float* q_w   = (const float*)d_in[4];
    const float* q_b   = (const float*)d_in[5];
    const float* k_w   = (const float*)d_in[6];
    const float* k_b   = (const float*)d_in[7];
    const float* v_w   = (const float*)d_in[8];
    const float* v_b   = (const float*)d_in[9];
    const float* o_w   = (const float*)d_in[10];
    const float* o_b   = (const float*)d_in[11];
    const float* ln_g  = (const float*)d_in[12];
    const float* ln_b  = (const float*)d_in[13];
    const float* out_w = (const float*)d_in[14];
    const float* out_b = (const float*)d_in[15];

    const size_t BNH = (size_t)B * N * H;
    float* h  = (float*)d_ws;
    float* ao = h + BNH;
    unsigned short* h_bf = (unsigned short*)(ao + BNH);
    unsigned short* qb = h_bf + BNH;
    unsigned short* kb = qb + BNH;
    unsigned short* vb = kb + BNH;
    unsigned* mbits = (unsigned*)(vb + BNH);
    unsigned short* x_bf = (unsigned short*)(mbits + (size_t)B * N * N / 32);
    unsigned short* wenc = x_bf + (size_t)B * N * D_IN;
    unsigned short* wqkv = wenc + H * D_IN;
    float* bqkv = (float*)(wqkv + L * 3 * H * H);

    pack_kernel<<<B * N * N / 32 / 256, 256, 0, stream>>>(adj, mbits);
    const int prep_total = B * N * D_IN + H * D_IN + L * 3 * H * H + L * 3 * H;
    prep_kernel<<<(prep_total + 255) / 256, 256, 0, stream>>>(
        x, enc_w, q_w, k_w, v_w, q_b, k_b, v_b, x_bf, wenc, wqkv, bqkv);
    enc_kernel<<<B * N / 64, 256, 0, stream>>>(x_bf, wenc, enc_b, h, h_bf);
    for (int i = 0; i < L; ++i) {
        qkv_kernel<<<B * N / 64, 256, 0, stream>>>(
            h_bf, wqkv + (size_t)i * 3 * H * H, bqkv + (size_t)i * 3 * H, qb, kb, vb);
        attn_kernel<<<B * HEADS * (N / 64), 256, 0, stream>>>(qb, kb, vb, mbits, ao);
        oln_kernel<<<B * N / 64, 256, 0, stream>>>(
            ao, o_w + (size_t)i * H * H, o_b + (size_t)i * H,
            ln_g + (size_t)i * H, ln_b + (size_t)i * H, h, h_bf);
    }
    final_kernel<<<B * N / 64, 256, 0, stream>>>(h, out_w, out_b, (float*)d_out);
}

// Round 5
// 128.659 us; speedup vs baseline: 10.8257x; 1.0910x over previous
//
#include <hip/hip_runtime.h>

#define B 8
#define N 1024
#define D_IN 64
#define H 128
#define HEADS 4
#define HD 32
#define L 2
#define EPS 1e-5f
#define NEG_BIG -1e30f
#define SCALE 0.17677669529663687f

typedef __attribute__((ext_vector_type(8))) short bf16x8;
typedef __attribute__((ext_vector_type(4))) float f32x4;

__device__ __forceinline__ unsigned short f2bf(float f) {
    unsigned u = __float_as_uint(f);
    u = u + 0x7fffu + ((u >> 16) & 1u);
    return (unsigned short)(u >> 16);
}
__device__ __forceinline__ float bf2f(unsigned short s) {
    return __uint_as_float(((unsigned)s) << 16);
}
__device__ __forceinline__ void gload_lds16(const void* g, void* l) {
    __builtin_amdgcn_global_load_lds(
        (const __attribute__((address_space(1))) unsigned int*)g,
        (__attribute__((address_space(3))) unsigned int*)l,
        16, 0, 0);
}

// ---------------- adj -> bitmask ----------------
__global__ __launch_bounds__(256) void pack_kernel(
    const float* __restrict__ adj, unsigned* __restrict__ mb) {
    int wd = blockIdx.x * 256 + threadIdx.x;
    const float4* src = (const float4*)(adj + (size_t)wd * 32);
    unsigned m = 0;
    #pragma unroll
    for (int c = 0; c < 8; ++c) {
        float4 f = src[c];
        if (f.x != 0.0f) m |= 1u << (c * 4 + 0);
        if (f.y != 0.0f) m |= 1u << (c * 4 + 1);
        if (f.z != 0.0f) m |= 1u << (c * 4 + 2);
        if (f.w != 0.0f) m |= 1u << (c * 4 + 3);
    }
    mb[wd] = m;
}

// ---- prep: bf16 conversions + weight hi/lo splits ----
__global__ __launch_bounds__(256) void prep_kernel(
    const float* __restrict__ x, const float* __restrict__ enc_w,
    const float* __restrict__ q_w, const float* __restrict__ k_w,
    const float* __restrict__ v_w, const float* __restrict__ q_b,
    const float* __restrict__ k_b, const float* __restrict__ v_b,
    const float* __restrict__ o_w, const float* __restrict__ out_w,
    unsigned short* __restrict__ x_bf, unsigned short* __restrict__ wenc,
    unsigned short* __restrict__ wqkv, float* __restrict__ bqkv,
    unsigned short* __restrict__ woh, unsigned short* __restrict__ wol,
    unsigned short* __restrict__ wfh, unsigned short* __restrict__ wfl) {
    int id = blockIdx.x * 256 + threadIdx.x;
    const int XN = B * N * D_IN;
    const int WE = H * D_IN;
    const int WQ = L * 3 * H * H;
    const int BQ = L * 3 * H;
    const int WO = L * H * H;
    const int WF = H * H;
    if (id < XN) { x_bf[id] = f2bf(x[id]); return; }
    id -= XN;
    if (id < WE) { wenc[id] = f2bf(enc_w[id]); return; }
    id -= WE;
    if (id < WQ) {
        int layer = id / (3 * H * H);
        int r = id % (3 * H * H);
        int mat = r / (H * H);
        int e = r % (H * H);
        const float* src = mat == 0 ? q_w : (mat == 1 ? k_w : v_w);
        float f = src[layer * H * H + e];
        if (mat == 0) f *= SCALE;
        wqkv[id] = f2bf(f);
        return;
    }
    id -= WQ;
    if (id < BQ) {
        int layer = id / (3 * H);
        int r = id % (3 * H);
        int mat = r / H;
        int e = r % H;
        const float* src = mat == 0 ? q_b : (mat == 1 ? k_b : v_b);
        float f = src[layer * H + e];
        if (mat == 0) f *= SCALE;
        bqkv[id] = f;
        return;
    }
    id -= BQ;
    if (id < WO) {
        float f = o_w[id];
        unsigned short hi = f2bf(f);
        woh[id] = hi;
        wol[id] = f2bf(f - bf2f(hi));
        return;
    }
    id -= WO;
    if (id < WF) {
        float f = out_w[id];
        unsigned short hi = f2bf(f);
        wfh[id] = hi;
        wfl[id] = f2bf(f - bf2f(hi));
    }
}

// ---------------- encoder MFMA ----------------
__global__ __launch_bounds__(256) void enc_kernel(
    const unsigned short* __restrict__ x_bf, const unsigned short* __restrict__ wenc,
    const float* __restrict__ eb, float* __restrict__ h, unsigned short* __restrict__ h_bf) {
    __shared__ unsigned short wt[H * D_IN];
    __shared__ unsigned short at[64 * D_IN];
    const int t = threadIdx.x;
    const int r0 = blockIdx.x * 64;
    const int w = t >> 6, lane = t & 63, g = lane >> 4, c16 = lane & 15;

    #pragma unroll
    for (int i = 0; i < 4; ++i) {
        int ci = i * 256 + t, row = ci >> 3, cr = ci & 7;
        gload_lds16(wenc + row * 64 + (cr ^ (row & 7)) * 8, (char*)wt + (i * 4 + w) * 1024);
    }
    #pragma unroll
    for (int i = 0; i < 2; ++i) {
        int ci = i * 256 + t, row = ci >> 3, cr = ci & 7;
        gload_lds16(x_bf + (size_t)(r0 + row) * 64 + (cr ^ (row & 7)) * 8,
                    (char*)at + (i * 4 + w) * 1024);
    }
    __syncthreads();

    const int arow = w * 16 + c16;
    bf16x8 a0 = *(const bf16x8*)(at + arow * 64 + ((g ^ (arow & 7)) * 8));
    bf16x8 a1 = *(const bf16x8*)(at + arow * 64 + (((4 + g) ^ (arow & 7)) * 8));
    f32x4 acc[8];
    #pragma unroll
    for (int sub = 0; sub < 8; ++sub) {
        int bcol = sub * 16 + c16;
        bf16x8 b0 = *(const bf16x8*)(wt + bcol * 64 + ((g ^ (bcol & 7)) * 8));
        bf16x8 b1 = *(const bf16x8*)(wt + bcol * 64 + (((4 + g) ^ (bcol & 7)) * 8));
        f32x4 z = {0.f, 0.f, 0.f, 0.f};
        z = __builtin_amdgcn_mfma_f32_16x16x32_bf16(a0, b0, z, 0, 0, 0);
        acc[sub] = __builtin_amdgcn_mfma_f32_16x16x32_bf16(a1, b1, z, 0, 0, 0);
    }
    #pragma unroll
    for (int sub = 0; sub < 8; ++sub) {
        int col = sub * 16 + c16;
        float bias = eb[col];
        #pragma unroll
        for (int rr = 0; rr < 4; ++rr) {
            int row = r0 + w * 16 + g * 4 + rr;
            float v = fmaxf(acc[sub][rr] + bias, 0.0f);
            h[(size_t)row * H + col] = v;
            h_bf[(size_t)row * H + col] = f2bf(v);
        }
    }
}

// ---------------- fused q/k/v MFMA ----------------
__global__ __launch_bounds__(256) void qkv_kernel(
    const unsigned short* __restrict__ h_bf, const unsigned short* __restrict__ wqkv_l,
    const float* __restrict__ bqkv_l,
    unsigned short* __restrict__ q, unsigned short* __restrict__ k,
    unsigned short* __restrict__ v) {
    __shared__ unsigned short wt[384 * 128];
    __shared__ unsigned short at[64 * 128];
    const int t = threadIdx.x;
    const int r0 = blockIdx.x * 64;
    const int w = t >> 6, lane = t & 63, g = lane >> 4, c16 = lane & 15;

    #pragma unroll
    for (int i = 0; i < 24; ++i) {
        int ci = i * 256 + t, row = ci >> 4, cr = ci & 15;
        gload_lds16(wqkv_l + (size_t)row * 128 + (cr ^ (row & 7)) * 8,
                    (char*)wt + (i * 4 + w) * 1024);
    }
    #pragma unroll
    for (int i = 0; i < 4; ++i) {
        int ci = i * 256 + t, row = ci >> 4, cr = ci & 15;
        gload_lds16(h_bf + (size_t)(r0 + row) * 128 + (cr ^ (row & 7)) * 8,
                    (char*)at + (i * 4 + w) * 1024);
    }
    __syncthreads();

    const int arow = w * 16 + c16;
    bf16x8 a[4];
    #pragma unroll
    for (int ks = 0; ks < 4; ++ks)
        a[ks] = *(const bf16x8*)(at + arow * 128 + (((ks * 4 + g) ^ (arow & 7)) * 8));

    f32x4 acc[24];
    #pragma unroll
    for (int sub = 0; sub < 24; ++sub) {
        int bcol = sub * 16 + c16;
        f32x4 z = {0.f, 0.f, 0.f, 0.f};
        #pragma unroll
        for (int ks = 0; ks < 4; ++ks) {
            bf16x8 bb = *(const bf16x8*)(wt + (size_t)bcol * 128 + (((ks * 4 + g) ^ (bcol & 7)) * 8));
            z = __builtin_amdgcn_mfma_f32_16x16x32_bf16(a[ks], bb, z, 0, 0, 0);
        }
        acc[sub] = z;
    }
    #pragma unroll
    for (int sub = 0; sub < 24; ++sub) {
        int mat = sub >> 3;
        int col = (sub & 7) * 16 + c16;
        float bias = bqkv_l[mat * H + col];
        unsigned short* dst = mat == 0 ? q : (mat == 1 ? k : v);
        #pragma unroll
        for (int rr = 0; rr < 4; ++rr) {
            int row = r0 + w * 16 + g * 4 + rr;
            dst[(size_t)row * H + col] = f2bf(acc[sub][rr] + bias);
        }
    }
}

// ---------------- MFMA flash attention, double-buffered K/V/mask ----------------
__global__ __launch_bounds__(256) void attn_kernel(
    const unsigned short* __restrict__ qg, const unsigned short* __restrict__ kg,
    const unsigned short* __restrict__ vg, const unsigned* __restrict__ mb,
    float* __restrict__ ao) {
    __shared__ unsigned short qt[64 * 32];
    __shared__ unsigned short kt[2][64 * 32];
    __shared__ unsigned short vt[2][32 * 72];
    __shared__ unsigned short pl[4][16 * 72];

    const int bid = blockIdx.x;
    const int itile = bid & 15;
    const int head = (bid >> 4) & 3;
    const int b = bid >> 6;
    const int i0 = itile * 64;

    const int t = threadIdx.x;
    const int w = t >> 6;
    const int lane = t & 63;
    const int g = lane >> 4;
    const int c16 = lane & 15;
    const int sw = c16 & 3;

    const int srow = t >> 2;
    const int sch = (t & 3) ^ ((t >> 2) & 3);

    // ---- prologue: Q + tile0 ----
    gload_lds16(qg + ((size_t)(b * N + i0 + srow)) * H + head * HD + sch * 8,
                (char*)qt + w * 1024);
    gload_lds16(kg + ((size_t)(b * N + srow)) * H + head * HD + sch * 8,
                (char*)kt[0] + w * 1024);
    int4 vreg = *(const int4*)(vg + ((size_t)(b * N + srow)) * H + head * HD + (t & 3) * 8);

    const unsigned* mrow = mb + (size_t)(b * N + i0 + w * 16 + g * 4) * (N / 32);
    unsigned long long am[4];
    #pragma unroll
    for (int r = 0; r < 4; ++r)
        am[r] = *(const unsigned long long*)(mrow + (size_t)r * (N / 32));

    {
        union { int4 i4; unsigned short u[8]; } uv; uv.i4 = vreg;
        #pragma unroll
        for (int dd = 0; dd < 8; ++dd)
            vt[0][((t & 3) * 8 + dd) * 72 + srow] = uv.u[dd];
    }
    __syncthreads();

    const bf16x8 qfrag = *(const bf16x8*)(qt + (w * 16 + c16) * 32 + (g ^ sw) * 8);

    f32x4 oacc[2];
    oacc[0] = (f32x4){0.f, 0.f, 0.f, 0.f};
    oacc[1] = (f32x4){0.f, 0.f, 0.f, 0.f};
    float mrun[4], lrun[4];
    #pragma unroll
    for (int r = 0; r < 4; ++r) { mrun[r] = NEG_BIG; lrun[r] = 0.0f; }

    for (int jt = 0; jt < 16; ++jt) {
        const int cur = jt & 1;
        // ---- prefetch tile jt+1 (K via gload_lds, V/mask into regs) ----
        int4 vregn;
        unsigned long long amn[4];
        if (jt < 15) {
            const int j0n = (jt + 1) * 64;
            gload_lds16(kg + ((size_t)(b * N + j0n + srow)) * H + head * HD + sch * 8,
                        (char*)kt[cur ^ 1] + w * 1024);
            vregn = *(const int4*)(vg + ((size_t)(b * N + j0n + srow)) * H + head * HD + (t & 3) * 8);
            #pragma unroll
            for (int r = 0; r < 4; ++r)
                amn[r] = *(const unsigned long long*)(mrow + (size_t)r * (N / 32) + (jt + 1) * 2);
        }
        // ---- S = Q K^T ----
        f32x4 sacc[4];
        #pragma unroll
        for (int sub = 0; sub < 4; ++sub) {
            bf16x8 bfrag = *(const bf16x8*)(kt[cur] + (sub * 16 + c16) * 32 + (g ^ sw) * 8);
            f32x4 z = {0.f, 0.f, 0.f, 0.f};
            sacc[sub] = __builtin_amdgcn_mfma_f32_16x16x32_bf16(qfrag, bfrag, z, 0, 0, 0);
        }
        // ---- mask + online softmax ----
        float pw[4][4], sf[4];
        #pragma unroll
        for (int r = 0; r < 4; ++r) {
            float sm[4];
            #pragma unroll
            for (int sub = 0; sub < 4; ++sub) {
                bool alive = (am[r] >> (sub * 16 + c16)) & 1ull;
                sm[sub] = alive ? sacc[sub][r] : NEG_BIG;
            }
            float mx = fmaxf(fmaxf(sm[0], sm[1]), fmaxf(sm[2], sm[3]));
            mx = fmaxf(mx, __shfl_xor(mx, 1));
            mx = fmaxf(mx, __shfl_xor(mx, 2));
            mx = fmaxf(mx, __shfl_xor(mx, 4));
            mx = fmaxf(mx, __shfl_xor(mx, 8));
            float mnew = fmaxf(mrun[r], mx);
            sf[r] = __expf(mrun[r] - mnew);
            mrun[r] = mnew;
            float rs = 0.f;
            #pragma unroll
            for (int sub = 0; sub < 4; ++sub) {
                float p = (sm[sub] > -0.9e30f) ? __expf(sm[sub] - mnew) : 0.0f;
                pw[sub][r] = p;
                rs += p;
            }
            rs += __shfl_xor(rs, 1);
            rs += __shfl_xor(rs, 2);
            rs += __shfl_xor(rs, 4);
            rs += __shfl_xor(rs, 8);
            lrun[r] = lrun[r] * sf[r] + rs;
        }
        // ---- P -> per-wave LDS ----
        #pragma unroll
        for (int r = 0; r < 4; ++r)
            #pragma unroll
            for (int sub = 0; sub < 4; ++sub)
                pl[w][(g * 4 + r) * 72 + sub * 16 + c16] = f2bf(pw[sub][r]);
        #pragma unroll
        for (int tt = 0; tt < 2; ++tt)
            #pragma unroll
            for (int r = 0; r < 4; ++r)
                oacc[tt][r] *= sf[r];
        asm volatile("s_waitcnt lgkmcnt(0)" ::: "memory");
        // ---- O += P V ----
        #pragma unroll
        for (int ks = 0; ks < 2; ++ks) {
            bf16x8 pa = *(const bf16x8*)(&pl[w][c16 * 72 + ks * 32 + g * 8]);
            #pragma unroll
            for (int tt = 0; tt < 2; ++tt) {
                bf16x8 vbf = *(const bf16x8*)(vt[cur] + (tt * 16 + c16) * 72 + ks * 32 + g * 8);
                oacc[tt] = __builtin_amdgcn_mfma_f32_16x16x32_bf16(pa, vbf, oacc[tt], 0, 0, 0);
            }
        }
        // ---- commit prefetched V/mask, one barrier per tile ----
        if (jt < 15) {
            union { int4 i4; unsigned short u[8]; } uv2; uv2.i4 = vregn;
            #pragma unroll
            for (int dd = 0; dd < 8; ++dd)
                vt[cur ^ 1][((t & 3) * 8 + dd) * 72 + srow] = uv2.u[dd];
            #pragma unroll
            for (int r = 0; r < 4; ++r) am[r] = amn[r];
            __syncthreads();
        }
    }
    #pragma unroll
    for (int r = 0; r < 4; ++r) {
        float inv = (lrun[r] > 0.0f) ? (1.0f / lrun[r]) : 0.0f;
        int irow = i0 + w * 16 + g * 4 + r;
        #pragma unroll
        for (int tt = 0; tt < 2; ++tt)
            ao[((size_t)(b * N + irow)) * H + head * HD + tt * 16 + c16] = oacc[tt][r] * inv;
    }
}

// ---- split fp32 tile -> bf16 hi/lo LDS (stride 130), activations only ----
__device__ __forceinline__ void stage_split(
    const float* __restrict__ src, unsigned short* hi, unsigned short* lo, int t) {
    #pragma unroll
    for (int it = 0; it < 8; ++it) {
        int idx4 = it * 256 + t;
        int row = idx4 >> 5, c4 = (idx4 & 31) * 4;
        float4 f = ((const float4*)src)[idx4];
        unsigned short h0 = f2bf(f.x), h1 = f2bf(f.y), h2 = f2bf(f.z), h3 = f2bf(f.w);
        unsigned short l0 = f2bf(f.x - bf2f(h0)), l1 = f2bf(f.y - bf2f(h1));
        unsigned short l2 = f2bf(f.z - bf2f(h2)), l3 = f2bf(f.w - bf2f(h3));
        *(unsigned*)(hi + row * 130 + c4)     = (unsigned)h0 | ((unsigned)h1 << 16);
        *(unsigned*)(hi + row * 130 + c4 + 2) = (unsigned)h2 | ((unsigned)h3 << 16);
        *(unsigned*)(lo + row * 130 + c4)     = (unsigned)l0 | ((unsigned)l1 << 16);
        *(unsigned*)(lo + row * 130 + c4 + 2) = (unsigned)l2 | ((unsigned)l3 << 16);
    }
}

// ---- 3-term split GEMM core: acc[sub] = A(hi+lo) x W(hi+lo) drop lo*lo ----
__device__ __forceinline__ void split_gemm(
    const unsigned short* ah, const unsigned short* al,
    const unsigned short* wh, const unsigned short* wl,
    int arow, int g, int c16, f32x4* acc) {
    bf16x8 ahf[4], alf[4];
    #pragma unroll
    for (int ks = 0; ks < 4; ++ks) {
        ahf[ks] = *(const bf16x8*)(ah + arow * 130 + ks * 32 + g * 8);
        alf[ks] = *(const bf16x8*)(al + arow * 130 + ks * 32 + g * 8);
    }
    #pragma unroll
    for (int sub = 0; sub < 8; ++sub) {
        int bcol = sub * 16 + c16;
        f32x4 z = {0.f, 0.f, 0.f, 0.f};
        #pragma unroll
        for (int ks = 0; ks < 4; ++ks) {
            bf16x8 bh = *(const bf16x8*)(wh + bcol * 128 + (((ks * 4 + g) ^ (bcol & 7)) * 8));
            bf16x8 bl = *(const bf16x8*)(wl + bcol * 128 + (((ks * 4 + g) ^ (bcol & 7)) * 8));
            z = __builtin_amdgcn_mfma_f32_16x16x32_bf16(ahf[ks], bh, z, 0, 0, 0);
            z = __builtin_amdgcn_mfma_f32_16x16x32_bf16(alf[ks], bh, z, 0, 0, 0);
            z = __builtin_amdgcn_mfma_f32_16x16x32_bf16(ahf[ks], bl, z, 0, 0, 0);
        }
        acc[sub] = z;
    }
}

__device__ __forceinline__ void stage_w(const unsigned short* __restrict__ src,
                                        unsigned short* dst, int t, int w) {
    #pragma unroll
    for (int i = 0; i < 8; ++i) {
        int ci = i * 256 + t, row = ci >> 4, cr = ci & 15;
        gload_lds16(src + (size_t)row * 128 + (cr ^ (row & 7)) * 8,
                    (char*)dst + (i * 4 + w) * 1024);
    }
}

// ------- layer-0: O-proj + LN + relu + residual -------
__global__ __launch_bounds__(256) void oln_kernel(
    const float* __restrict__ ao, const unsigned short* __restrict__ woh_l,
    const unsigned short* __restrict__ wol_l, const float* __restrict__ ob,
    const float* __restrict__ lng, const float* __restrict__ lnb,
    float* __restrict__ h, unsigned short* __restrict__ h_bf) {
    __shared__ unsigned short ah[64 * 130], al[64 * 130];
    __shared__ unsigned short wh[128 * 128], wl[128 * 128];
    const int t = threadIdx.x;
    const int r0 = blockIdx.x * 64;
    const int w = t >> 6, lane = t & 63, g = lane >> 4, c16 = lane & 15;

    stage_w(woh_l, wh, t, w);
    stage_w(wol_l, wl, t, w);
    stage_split(ao + (size_t)r0 * H, ah, al, t);
    __syncthreads();

    const int arow = w * 16 + c16;
    f32x4 acc[8];
    split_gemm(ah, al, wh, wl, arow, g, c16, acc);

    float val[8][4], s1[4] = {0, 0, 0, 0}, s2[4] = {0, 0, 0, 0};
    #pragma unroll
    for (int sub = 0; sub < 8; ++sub) {
        int col = sub * 16 + c16;
        float bias = ob[col];
        #pragma unroll
        for (int rr = 0; rr < 4; ++rr) {
            float vv = acc[sub][rr] + bias;
            val[sub][rr] = vv;
            s1[rr] += vv;
            s2[rr] += vv * vv;
        }
    }
    #pragma unroll
    for (int rr = 0; rr < 4; ++rr) {
        #pragma unroll
        for (int off = 1; off < 16; off <<= 1) {
            s1[rr] += __shfl_xor(s1[rr], off);
            s2[rr] += __shfl_xor(s2[rr], off);
        }
    }
    #pragma unroll
    for (int rr = 0; rr < 4; ++rr) {
        float mu = s1[rr] * (1.0f / H);
        float var = s2[rr] * (1.0f / H) - mu * mu;
        float rs = rsqrtf(var + EPS);
        int row = r0 + w * 16 + g * 4 + rr;
        #pragma unroll
        for (int sub = 0; sub < 8; ++sub) {
            int col = sub * 16 + c16;
            float y = (val[sub][rr] - mu) * rs * lng[col] + lnb[col];
            float hn = fmaxf(y, 0.0f) + h[(size_t)row * H + col];
            h[(size_t)row * H + col] = hn;
            h_bf[(size_t)row * H + col] = f2bf(hn);
        }
    }
}

// ------- layer-1 fused: O-proj + LN + relu + residual + final proj -> out -------
__global__ __launch_bounds__(256) void olnfinal_kernel(
    const float* __restrict__ ao, const unsigned short* __restrict__ woh_l,
    const unsigned short* __restrict__ wol_l, const float* __restrict__ ob,
    const float* __restrict__ lng, const float* __restrict__ lnb,
    const float* __restrict__ h, const unsigned short* __restrict__ wfh,
    const unsigned short* __restrict__ wfl, const float* __restrict__ fb,
    float* __restrict__ out) {
    __shared__ unsigned short ah[64 * 130], al[64 * 130];
    __shared__ unsigned short wh[128 * 128], wl[128 * 128];
    const int t = threadIdx.x;
    const int r0 = blockIdx.x * 64;
    const int w = t >> 6, lane = t & 63, g = lane >> 4, c16 = lane & 15;

    stage_w(woh_l, wh, t, w);
    stage_w(wol_l, wl, t, w);
    stage_split(ao + (size_t)r0 * H, ah, al, t);
    __syncthreads();

    const int arow = w * 16 + c16;
    f32x4 acc[8];
    split_gemm(ah, al, wh, wl, arow, g, c16, acc);

    float val[8][4], s1[4] = {0, 0, 0, 0}, s2[4] = {0, 0, 0, 0};
    #pragma unroll
    for (int sub = 0; sub < 8; ++sub) {
        int col = sub * 16 + c16;
        float bias = ob[col];
        #pragma unroll
        for (int rr = 0; rr < 4; ++rr) {
            float vv = acc[sub][rr] + bias;
            val[sub][rr] = vv;
            s1[rr] += vv;
            s2[rr] += vv * vv;
        }
    }
    #pragma unroll
    for (int rr = 0; rr < 4; ++rr) {
        #pragma unroll
        for (int off = 1; off < 16; off <<= 1) {
            s1[rr] += __shfl_xor(s1[rr], off);
            s2[rr] += __shfl_xor(s2[rr], off);
        }
    }
    __syncthreads();   // all lanes done reading ah/al/wh/wl
    // hn = relu(LN) + h  -> split hi/lo back into ah/al
    #pragma unroll
    for (int rr = 0; rr < 4; ++rr) {
        float mu = s1[rr] * (1.0f / H);
        float var = s2[rr] * (1.0f / H) - mu * mu;
        float rs = rsqrtf(var + EPS);
        int row = w * 16 + g * 4 + rr;
        #pragma unroll
        for (int sub = 0; sub < 8; ++sub) {
            int col = sub * 16 + c16;
            float y = (val[sub][rr] - mu) * rs * lng[col] + lnb[col];
            float hn = fmaxf(y, 0.0f) + h[(size_t)(r0 + row) * H + col];
            unsigned short hi = f2bf(hn);
            ah[row * 130 + col] = hi;
            al[row * 130 + col] = f2bf(hn - bf2f(hi));
        }
    }
    stage_w(wfh, wh, t, w);
    stage_w(wfl, wl, t, w);
    __syncthreads();

    f32x4 fac[8];
    split_gemm(ah, al, wh, wl, arow, g, c16, fac);
    #pragma unroll
    for (int sub = 0; sub < 8; ++sub) {
        int col = sub * 16 + c16;
        float bias = fb[col];
        #pragma unroll
        for (int rr = 0; rr < 4; ++rr) {
            int row = r0 + w * 16 + g * 4 + rr;
            out[(size_t)row * H + col] = fac[sub][rr] + bias;
        }
    }
}

extern "C" void kernel_launch(void* const* d_in, const int* in_sizes, int n_in,
                              void* d_out, int out_size, void* d_ws, size_t ws_size,
                              hipStream_t stream) {
    const float* x     = (const float*)d_in[0];
    const float* adj   = (const float*)d_in[1];
    const float* enc_w = (const float*)d_in[2];
    const float* enc_b = (const float*)d_in[3];
    const float* q_w   = (const float*)d_in[4];
    const float* q_b   = (const float*)d_in[5];
    const float* k_w   = (const float*)d_in[6];
    const float* k_b   = (const float*)d_in[7];
    const float* v_w   = (const float*)d_in[8];
    const float* v_b   = (const float*)d_in[9];
    const float* o_w   = (const float*)d_in[10];
    const float* o_b   = (const float*)d_in[11];
    const float* ln_g  = (const float*)d_in[12];
    const float* ln_b  = (const float*)d_in[13];
    const float* out_w = (const float*)d_in[14];
    const float* out_b = (const float*)d_in[15];

    const size_t BNH = (size_t)B * N * H;
    float* h  = (float*)d_ws;
    float* ao = h + BNH;
    unsigned short* h_bf = (unsigned short*)(ao + BNH);
    unsigned short* qb = h_bf + BNH;
    unsigned short* kb = qb + BNH;
    unsigned short* vb = kb + BNH;
    unsigned* mbits = (unsigned*)(vb + BNH);
    unsigned short* x_bf = (unsigned short*)(mbits + (size_t)B * N * N / 32);
    unsigned short* wenc = x_bf + (size_t)B * N * D_IN;
    unsigned short* wqkv = wenc + H * D_IN;
    float* bqkv = (float*)(wqkv + (size_t)L * 3 * H * H);
    unsigned short* woh = (unsigned short*)(bqkv + L * 3 * H);
    unsigned short* wol = woh + (size_t)L * H * H;
    unsigned short* wfh = wol + (size_t)L * H * H;
    unsigned short* wfl = wfh + (size_t)H * H;

    pack_kernel<<<B * N * N / 32 / 256, 256, 0, stream>>>(adj, mbits);
    const int prep_total = B * N * D_IN + H * D_IN + L * 3 * H * H + L * 3 * H
                         + L * H * H + H * H;
    prep_kernel<<<(prep_total + 255) / 256, 256, 0, stream>>>(
        x, enc_w, q_w, k_w, v_w, q_b, k_b, v_b, o_w, out_w,
        x_bf, wenc, wqkv, bqkv, woh, wol, wfh, wfl);
    enc_kernel<<<B * N / 64, 256, 0, stream>>>(x_bf, wenc, enc_b, h, h_bf);

    // layer 0
    qkv_kernel<<<B * N / 64, 256, 0, stream>>>(
        h_bf, wqkv, bqkv, qb, kb, vb);
    attn_kernel<<<B * HEADS * (N / 64), 256, 0, stream>>>(qb, kb, vb, mbits, ao);
    oln_kernel<<<B * N / 64, 256, 0, stream>>>(
        ao, woh, wol, o_b, ln_g, ln_b, h, h_bf);
    // layer 1 (+ final fused)
    qkv_kernel<<<B * N / 64, 256, 0, stream>>>(
        h_bf, wqkv + (size_t)3 * H * H, bqkv + 3 * H, qb, kb, vb);
    attn_kernel<<<B * HEADS * (N / 64), 256, 0, stream>>>(qb, kb, vb, mbits, ao);
    olnfinal_kernel<<<B * N / 64, 256, 0, stream>>>(
        ao, woh + (size_t)H * H, wol + (size_t)H * H, o_b + H,
        ln_g + H, ln_b + H, h, wfh, wfl, out_b, (float*)d_out);
}

// Round 7
// 100.135 us; speedup vs baseline: 13.9095x; 1.2849x over previous
//
#include <hip/hip_runtime.h>

#define B 8
#define N 1024
#define D_IN 64
#define H 128
#define HEADS 4
#define HD 32
#define L 2
#define EPS 1e-5f
#define NEG_BIG -1e30f
#define SCALE 0.17677669529663687f

typedef __attribute__((ext_vector_type(8))) short bf16x8;
typedef __attribute__((ext_vector_type(4))) float f32x4;

__device__ __forceinline__ unsigned short f2bf(float f) {
    unsigned u = __float_as_uint(f);
    u = u + 0x7fffu + ((u >> 16) & 1u);
    return (unsigned short)(u >> 16);
}
__device__ __forceinline__ float bf2f(unsigned short s) {
    return __uint_as_float(((unsigned)s) << 16);
}
__device__ __forceinline__ void gload_lds16(const void* g, void* l) {
    __builtin_amdgcn_global_load_lds(
        (const __attribute__((address_space(1))) unsigned int*)g,
        (__attribute__((address_space(3))) unsigned int*)l,
        16, 0, 0);
}

// ---------------- adj -> bitmask ----------------
__global__ __launch_bounds__(256) void pack_kernel(
    const float* __restrict__ adj, unsigned* __restrict__ mb) {
    int wd = blockIdx.x * 256 + threadIdx.x;
    const float4* src = (const float4*)(adj + (size_t)wd * 32);
    unsigned m = 0;
    #pragma unroll
    for (int c = 0; c < 8; ++c) {
        float4 f = src[c];
        if (f.x != 0.0f) m |= 1u << (c * 4 + 0);
        if (f.y != 0.0f) m |= 1u << (c * 4 + 1);
        if (f.z != 0.0f) m |= 1u << (c * 4 + 2);
        if (f.w != 0.0f) m |= 1u << (c * 4 + 3);
    }
    mb[wd] = m;
}

// ---- prep: bf16 conversions + weight hi/lo splits ----
__global__ __launch_bounds__(256) void prep_kernel(
    const float* __restrict__ x, const float* __restrict__ enc_w,
    const float* __restrict__ q_w, const float* __restrict__ k_w,
    const float* __restrict__ v_w, const float* __restrict__ q_b,
    const float* __restrict__ k_b, const float* __restrict__ v_b,
    const float* __restrict__ o_w, const float* __restrict__ out_w,
    unsigned short* __restrict__ x_bf, unsigned short* __restrict__ wenc,
    unsigned short* __restrict__ wqkv, float* __restrict__ bqkv,
    unsigned short* __restrict__ woh, unsigned short* __restrict__ wol,
    unsigned short* __restrict__ wfh, unsigned short* __restrict__ wfl) {
    int id = blockIdx.x * 256 + threadIdx.x;
    const int XN = B * N * D_IN;
    const int WE = H * D_IN;
    const int WQ = L * 3 * H * H;
    const int BQ = L * 3 * H;
    const int WO = L * H * H;
    const int WF = H * H;
    if (id < XN) { x_bf[id] = f2bf(x[id]); return; }
    id -= XN;
    if (id < WE) { wenc[id] = f2bf(enc_w[id]); return; }
    id -= WE;
    if (id < WQ) {
        int layer = id / (3 * H * H);
        int r = id % (3 * H * H);
        int mat = r / (H * H);
        int e = r % (H * H);
        const float* src = mat == 0 ? q_w : (mat == 1 ? k_w : v_w);
        float f = src[layer * H * H + e];
        if (mat == 0) f *= SCALE;
        wqkv[id] = f2bf(f);
        return;
    }
    id -= WQ;
    if (id < BQ) {
        int layer = id / (3 * H);
        int r = id % (3 * H);
        int mat = r / H;
        int e = r % H;
        const float* src = mat == 0 ? q_b : (mat == 1 ? k_b : v_b);
        float f = src[layer * H + e];
        if (mat == 0) f *= SCALE;
        bqkv[id] = f;
        return;
    }
    id -= BQ;
    if (id < WO) {
        float f = o_w[id];
        unsigned short hi = f2bf(f);
        woh[id] = hi;
        wol[id] = f2bf(f - bf2f(hi));
        return;
    }
    id -= WO;
    if (id < WF) {
        float f = out_w[id];
        unsigned short hi = f2bf(f);
        wfh[id] = hi;
        wfl[id] = f2bf(f - bf2f(hi));
    }
}

// ---------------- encoder MFMA ----------------
__global__ __launch_bounds__(256) void enc_kernel(
    const unsigned short* __restrict__ x_bf, const unsigned short* __restrict__ wenc,
    const float* __restrict__ eb, float* __restrict__ h, unsigned short* __restrict__ h_bf) {
    __shared__ unsigned short wt[H * D_IN];
    __shared__ unsigned short at[64 * D_IN];
    const int t = threadIdx.x;
    const int r0 = blockIdx.x * 64;
    const int w = t >> 6, lane = t & 63, g = lane >> 4, c16 = lane & 15;

    #pragma unroll
    for (int i = 0; i < 4; ++i) {
        int ci = i * 256 + t, row = ci >> 3, cr = ci & 7;
        gload_lds16(wenc + row * 64 + (cr ^ (row & 7)) * 8, (char*)wt + (i * 4 + w) * 1024);
    }
    #pragma unroll
    for (int i = 0; i < 2; ++i) {
        int ci = i * 256 + t, row = ci >> 3, cr = ci & 7;
        gload_lds16(x_bf + (size_t)(r0 + row) * 64 + (cr ^ (row & 7)) * 8,
                    (char*)at + (i * 4 + w) * 1024);
    }
    __syncthreads();

    const int arow = w * 16 + c16;
    bf16x8 a0 = *(const bf16x8*)(at + arow * 64 + ((g ^ (arow & 7)) * 8));
    bf16x8 a1 = *(const bf16x8*)(at + arow * 64 + (((4 + g) ^ (arow & 7)) * 8));
    f32x4 acc[8];
    #pragma unroll
    for (int sub = 0; sub < 8; ++sub) {
        int bcol = sub * 16 + c16;
        bf16x8 b0 = *(const bf16x8*)(wt + bcol * 64 + ((g ^ (bcol & 7)) * 8));
        bf16x8 b1 = *(const bf16x8*)(wt + bcol * 64 + (((4 + g) ^ (bcol & 7)) * 8));
        f32x4 z = {0.f, 0.f, 0.f, 0.f};
        z = __builtin_amdgcn_mfma_f32_16x16x32_bf16(a0, b0, z, 0, 0, 0);
        acc[sub] = __builtin_amdgcn_mfma_f32_16x16x32_bf16(a1, b1, z, 0, 0, 0);
    }
    #pragma unroll
    for (int sub = 0; sub < 8; ++sub) {
        int col = sub * 16 + c16;
        float bias = eb[col];
        #pragma unroll
        for (int rr = 0; rr < 4; ++rr) {
            int row = r0 + w * 16 + g * 4 + rr;
            float v = fmaxf(acc[sub][rr] + bias, 0.0f);
            h[(size_t)row * H + col] = v;
            h_bf[(size_t)row * H + col] = f2bf(v);
        }
    }
}

// ------- fused q/k/v MFMA; q,k row-major bf16; V stored TRANSPOSED (swizzled) -------
__global__ __launch_bounds__(256) void qkv_kernel(
    const unsigned short* __restrict__ h_bf, const unsigned short* __restrict__ wqkv_l,
    const float* __restrict__ bqkv_l,
    unsigned short* __restrict__ q, unsigned short* __restrict__ k,
    unsigned short* __restrict__ vT) {
    __shared__ unsigned short wt[384 * 128];
    __shared__ unsigned short at[64 * 128];
    const int t = threadIdx.x;
    const int r0 = blockIdx.x * 64;
    const int w = t >> 6, lane = t & 63, g = lane >> 4, c16 = lane & 15;

    #pragma unroll
    for (int i = 0; i < 24; ++i) {
        int ci = i * 256 + t, row = ci >> 4, cr = ci & 15;
        gload_lds16(wqkv_l + (size_t)row * 128 + (cr ^ (row & 7)) * 8,
                    (char*)wt + (i * 4 + w) * 1024);
    }
    #pragma unroll
    for (int i = 0; i < 4; ++i) {
        int ci = i * 256 + t, row = ci >> 4, cr = ci & 15;
        gload_lds16(h_bf + (size_t)(r0 + row) * 128 + (cr ^ (row & 7)) * 8,
                    (char*)at + (i * 4 + w) * 1024);
    }
    __syncthreads();

    const int arow = w * 16 + c16;
    bf16x8 a[4];
    #pragma unroll
    for (int ks = 0; ks < 4; ++ks)
        a[ks] = *(const bf16x8*)(at + arow * 128 + (((ks * 4 + g) ^ (arow & 7)) * 8));

    f32x4 acc[24];
    #pragma unroll
    for (int sub = 0; sub < 24; ++sub) {
        int bcol = sub * 16 + c16;
        f32x4 z = {0.f, 0.f, 0.f, 0.f};
        #pragma unroll
        for (int ks = 0; ks < 4; ++ks) {
            bf16x8 bb = *(const bf16x8*)(wt + (size_t)bcol * 128 + (((ks * 4 + g) ^ (bcol & 7)) * 8));
            z = __builtin_amdgcn_mfma_f32_16x16x32_bf16(a[ks], bb, z, 0, 0, 0);
        }
        acc[sub] = z;
    }
    #pragma unroll
    for (int sub = 0; sub < 24; ++sub) {
        int mat = sub >> 3;
        int col = (sub & 7) * 16 + c16;
        float bias = bqkv_l[mat * H + col];
        if (mat < 2) {
            unsigned short* dst = mat == 0 ? q : k;
            #pragma unroll
            for (int rr = 0; rr < 4; ++rr) {
                int row = r0 + w * 16 + g * 4 + rr;
                dst[(size_t)row * H + col] = f2bf(acc[sub][rr] + bias);
            }
        } else {
            // V transposed: vT[(b*HEADS+head)*HD + d][j], j-chunks pre-swizzled by d&7
            int hd = col >> 5, d = col & 31;
            int bb = r0 >> 10;
            int jbase = (r0 & (N - 1)) + w * 16 + g * 4;   // 4 consecutive j, same chunk
            int pos = (jbase & ~63) + ((((jbase >> 3) & 7) ^ (d & 7)) << 3) + (jbase & 7);
            float v0 = acc[sub][0] + bias, v1 = acc[sub][1] + bias;
            float v2 = acc[sub][2] + bias, v3 = acc[sub][3] + bias;
            unsigned lo, hi;
            asm("v_cvt_pk_bf16_f32 %0, %1, %2" : "=v"(lo) : "v"(v0), "v"(v1));
            asm("v_cvt_pk_bf16_f32 %0, %1, %2" : "=v"(hi) : "v"(v2), "v"(v3));
            uint2 pk2; pk2.x = lo; pk2.y = hi;
            *(uint2*)(vT + ((size_t)(bb * HEADS + hd) * HD + d) * N + pos) = pk2;
        }
    }
}

// ---------------- swapped-operand MFMA flash attention ----------------
// S^T = mfma(K, Q): lane (g,c16) holds S[i = w*16+c16][j = jsub*16+g*4+r]
// O^T = mfma(V^T, P): lane holds O[i = w*16+c16][d = dsub*16+g*4+r]; lrun/mrun lane-local.
__global__ __launch_bounds__(256) void attn_kernel(
    const unsigned short* __restrict__ qg, const unsigned short* __restrict__ kg,
    const unsigned short* __restrict__ vTg, const unsigned* __restrict__ mb,
    float* __restrict__ ao) {
    __shared__ unsigned short qt[64 * 32];
    __shared__ unsigned short kt[2][64 * 32];
    __shared__ unsigned short vt[2][32 * 64];   // V^T tile, linear (gload_lds), swizzled chunks
    __shared__ unsigned short pl[4][16 * 72];   // per-wave P, row = i (16), stride 72

    const int bid = blockIdx.x;
    const int itile = bid & 15;
    const int head = (bid >> 4) & 3;
    const int b = bid >> 6;
    const int i0 = itile * 64;
    const int bh = b * HEADS + head;

    const int t = threadIdx.x;
    const int w = t >> 6;
    const int lane = t & 63;
    const int g = lane >> 4;
    const int c16 = lane & 15;

    const int srow = t >> 2;                    // K/Q staging row
    const int sch = (t & 3) ^ ((t >> 2) & 3);   // K/Q chunk swizzle

    // ---- prologue: Q (once) + K/V^T/mask tile 0 ----
    gload_lds16(qg + ((size_t)(b * N + i0 + srow)) * H + head * HD + sch * 8,
                (char*)qt + w * 1024);
    gload_lds16(kg + ((size_t)(b * N + srow)) * H + head * HD + sch * 8,
                (char*)kt[0] + w * 1024);
    // V^T: lane l of wave w covers row d = (w*64+l)>>3, chunk (w*64+l)&7.
    // LDS dest = wave-uniform base w*1024 (+ lane*16 added by HW).
    gload_lds16(vTg + ((size_t)bh * HD + (t >> 3)) * N + (t & 7) * 8,
                (char*)vt[0] + w * 1024);

    const unsigned* mrow = mb + (size_t)(b * N + i0 + w * 16 + c16) * (N / 32);
    unsigned long long am = *(const unsigned long long*)mrow;

    __syncthreads();

    const int swq = c16 & 3;
    const bf16x8 qfrag = *(const bf16x8*)(qt + (w * 16 + c16) * 32 + ((g ^ swq) * 8));

    f32x4 oacc[2];
    oacc[0] = (f32x4){0.f, 0.f, 0.f, 0.f};
    oacc[1] = (f32x4){0.f, 0.f, 0.f, 0.f};
    float mrun = NEG_BIG, lrun = 0.0f;

    for (int jt = 0; jt < 16; ++jt) {
        const int cur = jt & 1;
        unsigned long long amn;
        if (jt < 15) {
            const int j0n = (jt + 1) * 64;
            gload_lds16(kg + ((size_t)(b * N + j0n + srow)) * H + head * HD + sch * 8,
                        (char*)kt[cur ^ 1] + w * 1024);
            gload_lds16(vTg + ((size_t)bh * HD + (t >> 3)) * N + j0n + (t & 7) * 8,
                        (char*)vt[cur ^ 1] + w * 1024);
            amn = *(const unsigned long long*)(mrow + (jt + 1) * 2);
        }
        // ---- S^T: 4 MFMAs, A = K rows, B = Q ----
        f32x4 sacc[4];
        #pragma unroll
        for (int jsub = 0; jsub < 4; ++jsub) {
            bf16x8 kfrag = *(const bf16x8*)(kt[cur] + (jsub * 16 + c16) * 32 + ((g ^ swq) * 8));
            f32x4 z = {0.f, 0.f, 0.f, 0.f};
            sacc[jsub] = __builtin_amdgcn_mfma_f32_16x16x32_bf16(kfrag, qfrag, z, 0, 0, 0);
        }
        // ---- mask + per-lane online softmax (row i = c16 lane-local) ----
        unsigned long long amg = am >> (g * 4);
        float sm[4][4], p[4][4];
        float mx = NEG_BIG;
        #pragma unroll
        for (int jsub = 0; jsub < 4; ++jsub)
            #pragma unroll
            for (int r = 0; r < 4; ++r) {
                bool alive = (amg >> (jsub * 16 + r)) & 1ull;
                float s = alive ? sacc[jsub][r] : NEG_BIG;
                sm[jsub][r] = s;
                mx = fmaxf(mx, s);
            }
        mx = fmaxf(mx, __shfl_xor(mx, 16));
        mx = fmaxf(mx, __shfl_xor(mx, 32));
        float mnew = fmaxf(mrun, mx);
        float sf = __expf(mrun - mnew);
        mrun = mnew;
        float rs = 0.0f;
        #pragma unroll
        for (int jsub = 0; jsub < 4; ++jsub)
            #pragma unroll
            for (int r = 0; r < 4; ++r) {
                float pv = (sm[jsub][r] > -0.9e30f) ? __expf(sm[jsub][r] - mnew) : 0.0f;
                p[jsub][r] = pv;
                rs += pv;
            }
        rs += __shfl_xor(rs, 16);
        rs += __shfl_xor(rs, 32);
        lrun = lrun * sf + rs;
        // ---- pack P (cvt_pk) -> per-wave LDS, 4 x b64 ----
        #pragma unroll
        for (int jsub = 0; jsub < 4; ++jsub) {
            unsigned lo, hi;
            asm("v_cvt_pk_bf16_f32 %0, %1, %2" : "=v"(lo) : "v"(p[jsub][0]), "v"(p[jsub][1]));
            asm("v_cvt_pk_bf16_f32 %0, %1, %2" : "=v"(hi) : "v"(p[jsub][2]), "v"(p[jsub][3]));
            uint2 pk2; pk2.x = lo; pk2.y = hi;
            *(uint2*)(&pl[w][c16 * 72 + jsub * 16 + g * 4]) = pk2;
        }
        // rescale O (sf lane-local) while P writes land
        #pragma unroll
        for (int dsub = 0; dsub < 2; ++dsub)
            #pragma unroll
            for (int r = 0; r < 4; ++r)
                oacc[dsub][r] *= sf;
        asm volatile("s_waitcnt lgkmcnt(0)" ::: "memory");
        // ---- O^T += V^T P : 2 ks x 2 dsub ----
        #pragma unroll
        for (int ks = 0; ks < 2; ++ks) {
            bf16x8 pa = *(const bf16x8*)(&pl[w][c16 * 72 + ks * 32 + g * 8]);
            #pragma unroll
            for (int dsub = 0; dsub < 2; ++dsub) {
                bf16x8 va = *(const bf16x8*)(vt[cur] + (dsub * 16 + c16) * 64 +
                                             (((ks * 4 + g) ^ (c16 & 7)) * 8));
                oacc[dsub] = __builtin_amdgcn_mfma_f32_16x16x32_bf16(va, pa, oacc[dsub], 0, 0, 0);
            }
        }
        if (jt < 15) {
            am = amn;
            __syncthreads();
        }
    }
    // ---- epilogue ----
    float inv = (lrun > 0.0f) ? (1.0f / lrun) : 0.0f;
    #pragma unroll
    for (int dsub = 0; dsub < 2; ++dsub) {
        float4 o;
        o.x = oacc[dsub][0] * inv; o.y = oacc[dsub][1] * inv;
        o.z = oacc[dsub][2] * inv; o.w = oacc[dsub][3] * inv;
        *(float4*)(ao + ((size_t)(b * N + i0 + w * 16 + c16)) * H +
                   head * HD + dsub * 16 + g * 4) = o;
    }
}

// ---- split fp32 tile -> bf16 hi/lo LDS (stride 130), activations only ----
__device__ __forceinline__ void stage_split(
    const float* __restrict__ src, unsigned short* hi, unsigned short* lo, int t) {
    #pragma unroll
    for (int it = 0; it < 8; ++it) {
        int idx4 = it * 256 + t;
        int row = idx4 >> 5, c4 = (idx4 & 31) * 4;
        float4 f = ((const float4*)src)[idx4];
        unsigned short h0 = f2bf(f.x), h1 = f2bf(f.y), h2 = f2bf(f.z), h3 = f2bf(f.w);
        unsigned short l0 = f2bf(f.x - bf2f(h0)), l1 = f2bf(f.y - bf2f(h1));
        unsigned short l2 = f2bf(f.z - bf2f(h2)), l3 = f2bf(f.w - bf2f(h3));
        *(unsigned*)(hi + row * 130 + c4)     = (unsigned)h0 | ((unsigned)h1 << 16);
        *(unsigned*)(hi + row * 130 + c4 + 2) = (unsigned)h2 | ((unsigned)h3 << 16);
        *(unsigned*)(lo + row * 130 + c4)     = (unsigned)l0 | ((unsigned)l1 << 16);
        *(unsigned*)(lo + row * 130 + c4 + 2) = (unsigned)l2 | ((unsigned)l3 << 16);
    }
}

// ---- 3-term split GEMM core ----
__device__ __forceinline__ void split_gemm(
    const unsigned short* ah, const unsigned short* al,
    const unsigned short* wh, const unsigned short* wl,
    int arow, int g, int c16, f32x4* acc) {
    bf16x8 ahf[4], alf[4];
    #pragma unroll
    for (int ks = 0; ks < 4; ++ks) {
        ahf[ks] = *(const bf16x8*)(ah + arow * 130 + ks * 32 + g * 8);
        alf[ks] = *(const bf16x8*)(al + arow * 130 + ks * 32 + g * 8);
    }
    #pragma unroll
    for (int sub = 0; sub < 8; ++sub) {
        int bcol = sub * 16 + c16;
        f32x4 z = {0.f, 0.f, 0.f, 0.f};
        #pragma unroll
        for (int ks = 0; ks < 4; ++ks) {
            bf16x8 bh = *(const bf16x8*)(wh + bcol * 128 + (((ks * 4 + g) ^ (bcol & 7)) * 8));
            bf16x8 bl = *(const bf16x8*)(wl + bcol * 128 + (((ks * 4 + g) ^ (bcol & 7)) * 8));
            z = __builtin_amdgcn_mfma_f32_16x16x32_bf16(ahf[ks], bh, z, 0, 0, 0);
            z = __builtin_amdgcn_mfma_f32_16x16x32_bf16(alf[ks], bh, z, 0, 0, 0);
            z = __builtin_amdgcn_mfma_f32_16x16x32_bf16(ahf[ks], bl, z, 0, 0, 0);
        }
        acc[sub] = z;
    }
}

__device__ __forceinline__ void stage_w(const unsigned short* __restrict__ src,
                                        unsigned short* dst, int t, int w) {
    #pragma unroll
    for (int i = 0; i < 8; ++i) {
        int ci = i * 256 + t, row = ci >> 4, cr = ci & 15;
        gload_lds16(src + (size_t)row * 128 + (cr ^ (row & 7)) * 8,
                    (char*)dst + (i * 4 + w) * 1024);
    }
}

// ------- layer-0: O-proj + LN + relu + residual -------
__global__ __launch_bounds__(256) void oln_kernel(
    const float* __restrict__ ao, const unsigned short* __restrict__ woh_l,
    const unsigned short* __restrict__ wol_l, const float* __restrict__ ob,
    const float* __restrict__ lng, const float* __restrict__ lnb,
    float* __restrict__ h, unsigned short* __restrict__ h_bf) {
    __shared__ unsigned short ah[64 * 130], al[64 * 130];
    __shared__ unsigned short wh[128 * 128], wl[128 * 128];
    const int t = threadIdx.x;
    const int r0 = blockIdx.x * 64;
    const int w = t >> 6, lane = t & 63, g = lane >> 4, c16 = lane & 15;

    stage_w(woh_l, wh, t, w);
    stage_w(wol_l, wl, t, w);
    stage_split(ao + (size_t)r0 * H, ah, al, t);
    __syncthreads();

    const int arow = w * 16 + c16;
    f32x4 acc[8];
    split_gemm(ah, al, wh, wl, arow, g, c16, acc);

    float val[8][4], s1[4] = {0, 0, 0, 0}, s2[4] = {0, 0, 0, 0};
    #pragma unroll
    for (int sub = 0; sub < 8; ++sub) {
        int col = sub * 16 + c16;
        float bias = ob[col];
        #pragma unroll
        for (int rr = 0; rr < 4; ++rr) {
            float vv = acc[sub][rr] + bias;
            val[sub][rr] = vv;
            s1[rr] += vv;
            s2[rr] += vv * vv;
        }
    }
    #pragma unroll
    for (int rr = 0; rr < 4; ++rr) {
        #pragma unroll
        for (int off = 1; off < 16; off <<= 1) {
            s1[rr] += __shfl_xor(s1[rr], off);
            s2[rr] += __shfl_xor(s2[rr], off);
        }
    }
    #pragma unroll
    for (int rr = 0; rr < 4; ++rr) {
        float mu = s1[rr] * (1.0f / H);
        float var = s2[rr] * (1.0f / H) - mu * mu;
        float rsn = rsqrtf(var + EPS);
        int row = r0 + w * 16 + g * 4 + rr;
        #pragma unroll
        for (int sub = 0; sub < 8; ++sub) {
            int col = sub * 16 + c16;
            float y = (val[sub][rr] - mu) * rsn * lng[col] + lnb[col];
            float hn = fmaxf(y, 0.0f) + h[(size_t)row * H + col];
            h[(size_t)row * H + col] = hn;
            h_bf[(size_t)row * H + col] = f2bf(hn);
        }
    }
}

// ------- layer-1 fused: O-proj + LN + relu + residual + final proj -> out -------
__global__ __launch_bounds__(256) void olnfinal_kernel(
    const float* __restrict__ ao, const unsigned short* __restrict__ woh_l,
    const unsigned short* __restrict__ wol_l, const float* __restrict__ ob,
    const float* __restrict__ lng, const float* __restrict__ lnb,
    const float* __restrict__ h, const unsigned short* __restrict__ wfh,
    const unsigned short* __restrict__ wfl, const float* __restrict__ fb,
    float* __restrict__ out) {
    __shared__ unsigned short ah[64 * 130], al[64 * 130];
    __shared__ unsigned short wh[128 * 128], wl[128 * 128];
    const int t = threadIdx.x;
    const int r0 = blockIdx.x * 64;
    const int w = t >> 6, lane = t & 63, g = lane >> 4, c16 = lane & 15;

    stage_w(woh_l, wh, t, w);
    stage_w(wol_l, wl, t, w);
    stage_split(ao + (size_t)r0 * H, ah, al, t);
    __syncthreads();

    const int arow = w * 16 + c16;
    f32x4 acc[8];
    split_gemm(ah, al, wh, wl, arow, g, c16, acc);

    float val[8][4], s1[4] = {0, 0, 0, 0}, s2[4] = {0, 0, 0, 0};
    #pragma unroll
    for (int sub = 0; sub < 8; ++sub) {
        int col = sub * 16 + c16;
        float bias = ob[col];
        #pragma unroll
        for (int rr = 0; rr < 4; ++rr) {
            float vv = acc[sub][rr] + bias;
            val[sub][rr] = vv;
            s1[rr] += vv;
            s2[rr] += vv * vv;
        }
    }
    #pragma unroll
    for (int rr = 0; rr < 4; ++rr) {
        #pragma unroll
        for (int off = 1; off < 16; off <<= 1) {
            s1[rr] += __shfl_xor(s1[rr], off);
            s2[rr] += __shfl_xor(s2[rr], off);
        }
    }
    __syncthreads();
    #pragma unroll
    for (int rr = 0; rr < 4; ++rr) {
        float mu = s1[rr] * (1.0f / H);
        float var = s2[rr] * (1.0f / H) - mu * mu;
        float rsn = rsqrtf(var + EPS);
        int row = w * 16 + g * 4 + rr;
        #pragma unroll
        for (int sub = 0; sub < 8; ++sub) {
            int col = sub * 16 + c16;
            float y = (val[sub][rr] - mu) * rsn * lng[col] + lnb[col];
            float hn = fmaxf(y, 0.0f) + h[(size_t)(r0 + row) * H + col];
            unsigned short hi = f2bf(hn);
            ah[row * 130 + col] = hi;
            al[row * 130 + col] = f2bf(hn - bf2f(hi));
        }
    }
    stage_w(wfh, wh, t, w);
    stage_w(wfl, wl, t, w);
    __syncthreads();

    f32x4 fac[8];
    split_gemm(ah, al, wh, wl, arow, g, c16, fac);
    #pragma unroll
    for (int sub = 0; sub < 8; ++sub) {
        int col = sub * 16 + c16;
        float bias = fb[col];
        #pragma unroll
        for (int rr = 0; rr < 4; ++rr) {
            int row = r0 + w * 16 + g * 4 + rr;
            out[(size_t)row * H + col] = fac[sub][rr] + bias;
        }
    }
}

extern "C" void kernel_launch(void* const* d_in, const int* in_sizes, int n_in,
                              void* d_out, int out_size, void* d_ws, size_t ws_size,
                              hipStream_t stream) {
    const float* x     = (const float*)d_in[0];
    const float* adj   = (const float*)d_in[1];
    const float* enc_w = (const float*)d_in[2];
    const float* enc_b = (const float*)d_in[3];
    const float* q_w   = (const float*)d_in[4];
    const float* q_b   = (const float*)d_in[5];
    const float* k_w   = (const float*)d_in[6];
    const float* k_b   = (const float*)d_in[7];
    const float* v_w   = (const float*)d_in[8];
    const float* v_b   = (const float*)d_in[9];
    const float* o_w   = (const float*)d_in[10];
    const float* o_b   = (const float*)d_in[11];
    const float* ln_g  = (const float*)d_in[12];
    const float* ln_b  = (const float*)d_in[13];
    const float* out_w = (const float*)d_in[14];
    const float* out_b = (const float*)d_in[15];

    const size_t BNH = (size_t)B * N * H;
    float* h  = (float*)d_ws;
    float* ao = h + BNH;
    unsigned short* h_bf = (unsigned short*)(ao + BNH);
    unsigned short* qb = h_bf + BNH;
    unsigned short* kb = qb + BNH;
    unsigned short* vT = kb + BNH;
    unsigned* mbits = (unsigned*)(vT + BNH);
    unsigned short* x_bf = (unsigned short*)(mbits + (size_t)B * N * N / 32);
    unsigned short* wenc = x_bf + (size_t)B * N * D_IN;
    unsigned short* wqkv = wenc + H * D_IN;
    float* bqkv = (float*)(wqkv + (size_t)L * 3 * H * H);
    unsigned short* woh = (unsigned short*)(bqkv + L * 3 * H);
    unsigned short* wol = woh + (size_t)L * H * H;
    unsigned short* wfh = wol + (size_t)L * H * H;
    unsigned short* wfl = wfh + (size_t)H * H;

    pack_kernel<<<B * N * N / 32 / 256, 256, 0, stream>>>(adj, mbits);
    const int prep_total = B * N * D_IN + H * D_IN + L * 3 * H * H + L * 3 * H
                         + L * H * H + H * H;
    prep_kernel<<<(prep_total + 255) / 256, 256, 0, stream>>>(
        x, enc_w, q_w, k_w, v_w, q_b, k_b, v_b, o_w, out_w,
        x_bf, wenc, wqkv, bqkv, woh, wol, wfh, wfl);
    enc_kernel<<<B * N / 64, 256, 0, stream>>>(x_bf, wenc, enc_b, h, h_bf);

    // layer 0
    qkv_kernel<<<B * N / 64, 256, 0, stream>>>(h_bf, wqkv, bqkv, qb, kb, vT);
    attn_kernel<<<B * HEADS * (N / 64), 256, 0, stream>>>(qb, kb, vT, mbits, ao);
    oln_kernel<<<B * N / 64, 256, 0, stream>>>(
        ao, woh, wol, o_b, ln_g, ln_b, h, h_bf);
    // layer 1 (+ final fused)
    qkv_kernel<<<B * N / 64, 256, 0, stream>>>(
        h_bf, wqkv + (size_t)3 * H * H, bqkv + 3 * H, qb, kb, vT);
    attn_kernel<<<B * HEADS * (N / 64), 256, 0, stream>>>(qb, kb, vT, mbits, ao);
    olnfinal_kernel<<<B * N / 64, 256, 0, stream>>>(
        ao, woh + (size_t)H * H, wol + (size_t)H * H, o_b + H,
        ln_g + H, ln_b + H, h, wfh, wfl, out_b, (float*)d_out);
}

// Round 9
// 95.209 us; speedup vs baseline: 14.6292x; 1.0517x over previous
//
#include <hip/hip_runtime.h>

#define B 8
#define N 1024
#define D_IN 64
#define H 128
#define HEADS 4
#define HD 32
#define L 2
#define EPS 1e-5f
#define NEG_BIG -1e30f
#define SCALE 0.17677669529663687f

typedef __attribute__((ext_vector_type(8))) short bf16x8;
typedef __attribute__((ext_vector_type(4))) float f32x4;

__device__ __forceinline__ unsigned short f2bf(float f) {
    unsigned u = __float_as_uint(f);
    u = u + 0x7fffu + ((u >> 16) & 1u);
    return (unsigned short)(u >> 16);
}
__device__ __forceinline__ float bf2f(unsigned short s) {
    return __uint_as_float(((unsigned)s) << 16);
}
__device__ __forceinline__ void gload_lds16(const void* g, void* l) {
    __builtin_amdgcn_global_load_lds(
        (const __attribute__((address_space(1))) unsigned int*)g,
        (__attribute__((address_space(3))) unsigned int*)l,
        16, 0, 0);
}

// ---------------- adj -> bitmask ----------------
__global__ __launch_bounds__(256) void pack_kernel(
    const float* __restrict__ adj, unsigned* __restrict__ mb) {
    int wd = blockIdx.x * 256 + threadIdx.x;
    const float4* src = (const float4*)(adj + (size_t)wd * 32);
    unsigned m = 0;
    #pragma unroll
    for (int c = 0; c < 8; ++c) {
        float4 f = src[c];
        if (f.x != 0.0f) m |= 1u << (c * 4 + 0);
        if (f.y != 0.0f) m |= 1u << (c * 4 + 1);
        if (f.z != 0.0f) m |= 1u << (c * 4 + 2);
        if (f.w != 0.0f) m |= 1u << (c * 4 + 3);
    }
    mb[wd] = m;
}

// ---- prep: bf16 conversions + weight hi/lo splits ----
__global__ __launch_bounds__(256) void prep_kernel(
    const float* __restrict__ x, const float* __restrict__ enc_w,
    const float* __restrict__ q_w, const float* __restrict__ k_w,
    const float* __restrict__ v_w, const float* __restrict__ q_b,
    const float* __restrict__ k_b, const float* __restrict__ v_b,
    const float* __restrict__ o_w, const float* __restrict__ out_w,
    unsigned short* __restrict__ x_bf, unsigned short* __restrict__ wenc,
    unsigned short* __restrict__ wqkv, float* __restrict__ bqkv,
    unsigned short* __restrict__ woh, unsigned short* __restrict__ wol,
    unsigned short* __restrict__ wfh, unsigned short* __restrict__ wfl) {
    int id = blockIdx.x * 256 + threadIdx.x;
    const int XN = B * N * D_IN;
    const int WE = H * D_IN;
    const int WQ = L * 3 * H * H;
    const int BQ = L * 3 * H;
    const int WO = L * H * H;
    const int WF = H * H;
    if (id < XN) { x_bf[id] = f2bf(x[id]); return; }
    id -= XN;
    if (id < WE) { wenc[id] = f2bf(enc_w[id]); return; }
    id -= WE;
    if (id < WQ) {
        int layer = id / (3 * H * H);
        int r = id % (3 * H * H);
        int mat = r / (H * H);
        int e = r % (H * H);
        const float* src = mat == 0 ? q_w : (mat == 1 ? k_w : v_w);
        float f = src[layer * H * H + e];
        if (mat == 0) f *= SCALE;
        wqkv[id] = f2bf(f);
        return;
    }
    id -= WQ;
    if (id < BQ) {
        int layer = id / (3 * H);
        int r = id % (3 * H);
        int mat = r / H;
        int e = r % H;
        const float* src = mat == 0 ? q_b : (mat == 1 ? k_b : v_b);
        float f = src[layer * H + e];
        if (mat == 0) f *= SCALE;
        bqkv[id] = f;
        return;
    }
    id -= BQ;
    if (id < WO) {
        float f = o_w[id];
        unsigned short hi = f2bf(f);
        woh[id] = hi;
        wol[id] = f2bf(f - bf2f(hi));
        return;
    }
    id -= WO;
    if (id < WF) {
        float f = out_w[id];
        unsigned short hi = f2bf(f);
        wfh[id] = hi;
        wfl[id] = f2bf(f - bf2f(hi));
    }
}

// ---------------- encoder MFMA ----------------
__global__ __launch_bounds__(256) void enc_kernel(
    const unsigned short* __restrict__ x_bf, const unsigned short* __restrict__ wenc,
    const float* __restrict__ eb, float* __restrict__ h, unsigned short* __restrict__ h_bf) {
    __shared__ unsigned short wt[H * D_IN];
    __shared__ unsigned short at[64 * D_IN];
    const int t = threadIdx.x;
    const int r0 = blockIdx.x * 64;
    const int w = t >> 6, lane = t & 63, g = lane >> 4, c16 = lane & 15;

    #pragma unroll
    for (int i = 0; i < 4; ++i) {
        int ci = i * 256 + t, row = ci >> 3, cr = ci & 7;
        gload_lds16(wenc + row * 64 + (cr ^ (row & 7)) * 8, (char*)wt + (i * 4 + w) * 1024);
    }
    #pragma unroll
    for (int i = 0; i < 2; ++i) {
        int ci = i * 256 + t, row = ci >> 3, cr = ci & 7;
        gload_lds16(x_bf + (size_t)(r0 + row) * 64 + (cr ^ (row & 7)) * 8,
                    (char*)at + (i * 4 + w) * 1024);
    }
    __syncthreads();

    const int arow = w * 16 + c16;
    bf16x8 a0 = *(const bf16x8*)(at + arow * 64 + ((g ^ (arow & 7)) * 8));
    bf16x8 a1 = *(const bf16x8*)(at + arow * 64 + (((4 + g) ^ (arow & 7)) * 8));
    f32x4 acc[8];
    #pragma unroll
    for (int sub = 0; sub < 8; ++sub) {
        int bcol = sub * 16 + c16;
        bf16x8 b0 = *(const bf16x8*)(wt + bcol * 64 + ((g ^ (bcol & 7)) * 8));
        bf16x8 b1 = *(const bf16x8*)(wt + bcol * 64 + (((4 + g) ^ (bcol & 7)) * 8));
        f32x4 z = {0.f, 0.f, 0.f, 0.f};
        z = __builtin_amdgcn_mfma_f32_16x16x32_bf16(a0, b0, z, 0, 0, 0);
        acc[sub] = __builtin_amdgcn_mfma_f32_16x16x32_bf16(a1, b1, z, 0, 0, 0);
    }
    #pragma unroll
    for (int sub = 0; sub < 8; ++sub) {
        int col = sub * 16 + c16;
        float bias = eb[col];
        #pragma unroll
        for (int rr = 0; rr < 4; ++rr) {
            int row = r0 + w * 16 + g * 4 + rr;
            float v = fmaxf(acc[sub][rr] + bias, 0.0f);
            h[(size_t)row * H + col] = v;
            h_bf[(size_t)row * H + col] = f2bf(v);
        }
    }
}

// ------- fused q/k/v MFMA, col-split (grid 256): block = 64 rows x 192 cols -------
__global__ __launch_bounds__(256) void qkv_kernel(
    const unsigned short* __restrict__ h_bf, const unsigned short* __restrict__ wqkv_l,
    const float* __restrict__ bqkv_l,
    unsigned short* __restrict__ q, unsigned short* __restrict__ k,
    unsigned short* __restrict__ vT) {
    __shared__ unsigned short wt[192 * 128];   // 48 KB
    __shared__ unsigned short at[64 * 128];    // 16 KB
    const int t = threadIdx.x;
    const int r0 = (blockIdx.x >> 1) * 64;
    const int ch = blockIdx.x & 1;
    const int w = t >> 6, lane = t & 63, g = lane >> 4, c16 = lane & 15;
    const unsigned short* wsrc = wqkv_l + (size_t)ch * 192 * 128;

    #pragma unroll
    for (int i = 0; i < 12; ++i) {
        int ci = i * 256 + t, row = ci >> 4, cr = ci & 15;
        gload_lds16(wsrc + (size_t)row * 128 + (cr ^ (row & 7)) * 8,
                    (char*)wt + (i * 4 + w) * 1024);
    }
    #pragma unroll
    for (int i = 0; i < 4; ++i) {
        int ci = i * 256 + t, row = ci >> 4, cr = ci & 15;
        gload_lds16(h_bf + (size_t)(r0 + row) * 128 + (cr ^ (row & 7)) * 8,
                    (char*)at + (i * 4 + w) * 1024);
    }
    __syncthreads();

    const int arow = w * 16 + c16;
    bf16x8 a[4];
    #pragma unroll
    for (int ks = 0; ks < 4; ++ks)
        a[ks] = *(const bf16x8*)(at + arow * 128 + (((ks * 4 + g) ^ (arow & 7)) * 8));

    f32x4 acc[12];
    #pragma unroll
    for (int sub = 0; sub < 12; ++sub) {
        int bcol = sub * 16 + c16;           // local row in wt
        f32x4 z = {0.f, 0.f, 0.f, 0.f};
        #pragma unroll
        for (int ks = 0; ks < 4; ++ks) {
            bf16x8 bb = *(const bf16x8*)(wt + (size_t)bcol * 128 + (((ks * 4 + g) ^ (bcol & 7)) * 8));
            z = __builtin_amdgcn_mfma_f32_16x16x32_bf16(a[ks], bb, z, 0, 0, 0);
        }
        acc[sub] = z;
    }
    #pragma unroll
    for (int sub = 0; sub < 12; ++sub) {
        int gcol = ch * 192 + sub * 16 + c16;
        int mat = gcol >> 7;
        int colin = gcol & 127;
        float bias = bqkv_l[mat * H + colin];
        if (mat < 2) {
            unsigned short* dst = mat == 0 ? q : k;
            #pragma unroll
            for (int rr = 0; rr < 4; ++rr) {
                int row = r0 + w * 16 + g * 4 + rr;
                dst[(size_t)row * H + colin] = f2bf(acc[sub][rr] + bias);
            }
        } else {
            // V transposed: vT[(b*HEADS+head)*HD + d][j], j-chunks pre-swizzled by d&7
            int hd = colin >> 5, d = colin & 31;
            int bb = r0 >> 10;
            int jbase = (r0 & (N - 1)) + w * 16 + g * 4;
            int pos = (jbase & ~63) + ((((jbase >> 3) & 7) ^ (d & 7)) << 3) + (jbase & 7);
            float v0 = acc[sub][0] + bias, v1 = acc[sub][1] + bias;
            float v2 = acc[sub][2] + bias, v3 = acc[sub][3] + bias;
            unsigned lo, hi;
            asm("v_cvt_pk_bf16_f32 %0, %1, %2" : "=v"(lo) : "v"(v0), "v"(v1));
            asm("v_cvt_pk_bf16_f32 %0, %1, %2" : "=v"(hi) : "v"(v2), "v"(v3));
            uint2 pk2; pk2.x = lo; pk2.y = hi;
            *(uint2*)(vT + ((size_t)(bb * HEADS + hd) * HD + d) * N + pos) = pk2;
        }
    }
}

// ---------------- swapped-operand MFMA flash attention, KVBLK=128 ----------------
// S^T = mfma(K, Q): lane (g,c16) holds S[i = w*16+c16][j = jsub*16+g*4+r], jsub 0..7
// O^T = mfma(V^T, P): lane holds O[i = w*16+c16][d = dsub*16+g*4+r]
__global__ __launch_bounds__(256) void attn_kernel(
    const unsigned short* __restrict__ qg, const unsigned short* __restrict__ kg,
    const unsigned short* __restrict__ vTg, const unsigned* __restrict__ mb,
    float* __restrict__ ao) {
    __shared__ unsigned short qt[64 * 32];          // 4 KB
    __shared__ unsigned short kt[2][128 * 32];      // 16 KB
    __shared__ unsigned short vt[2][32 * 128];      // 16 KB (verbatim copy of stored-swizzled vT)
    __shared__ unsigned short pl[4][16 * 136];      // 17 KB per-wave P, stride 136

    const int bid = blockIdx.x;
    const int itile = bid & 15;
    const int head = (bid >> 4) & 3;
    const int b = bid >> 6;
    const int i0 = itile * 64;
    const int bh = b * HEADS + head;

    const int t = threadIdx.x;
    const int w = t >> 6;
    const int lane = t & 63;
    const int g = lane >> 4;
    const int c16 = lane & 15;

    const int srow = t >> 2;                    // K/Q staging row (0..63 per call)
    const int sch = (t & 3) ^ ((t >> 2) & 3);   // K/Q chunk swizzle

    // ---- prologue: Q (once) + K/V^T/mask tile 0 ----
    gload_lds16(qg + ((size_t)(b * N + i0 + srow)) * H + head * HD + sch * 8,
                (char*)qt + w * 1024);
    #pragma unroll
    for (int i = 0; i < 2; ++i)
        gload_lds16(kg + ((size_t)(b * N + i * 64 + srow)) * H + head * HD + sch * 8,
                    (char*)kt[0] + i * 4096 + w * 1024);
    // V^T staged VERBATIM (stored layout already d-swizzled by qkv); read side undoes it.
    #pragma unroll
    for (int i = 0; i < 2; ++i) {
        int d = i * 16 + (t >> 4), c = t & 15;
        gload_lds16(vTg + ((size_t)bh * HD + d) * N + c * 8,
                    (char*)vt[0] + i * 4096 + w * 1024);
    }
    const unsigned* mrow = mb + (size_t)(b * N + i0 + w * 16 + c16) * (N / 32);
    uint4 am = *(const uint4*)mrow;

    __syncthreads();

    const int swq = c16 & 3;
    const bf16x8 qfrag = *(const bf16x8*)(qt + (w * 16 + c16) * 32 + ((g ^ swq) * 8));

    f32x4 oacc[2];
    oacc[0] = (f32x4){0.f, 0.f, 0.f, 0.f};
    oacc[1] = (f32x4){0.f, 0.f, 0.f, 0.f};
    float mrun = NEG_BIG, lrun = 0.0f;

    for (int jt = 0; jt < 8; ++jt) {
        const int cur = jt & 1;
        uint4 amn;
        if (jt < 7) {
            const int j0n = (jt + 1) * 128;
            #pragma unroll
            for (int i = 0; i < 2; ++i)
                gload_lds16(kg + ((size_t)(b * N + j0n + i * 64 + srow)) * H + head * HD + sch * 8,
                            (char*)kt[cur ^ 1] + i * 4096 + w * 1024);
            #pragma unroll
            for (int i = 0; i < 2; ++i) {
                int d = i * 16 + (t >> 4), c = t & 15;
                gload_lds16(vTg + ((size_t)bh * HD + d) * N + j0n + c * 8,
                            (char*)vt[cur ^ 1] + i * 4096 + w * 1024);
            }
            amn = *(const uint4*)(mrow + (jt + 1) * 4);
        }
        // ---- S^T: 8 MFMAs, A = K rows, B = Q ----
        f32x4 sacc[8];
        #pragma unroll
        for (int jsub = 0; jsub < 8; ++jsub) {
            bf16x8 kfrag = *(const bf16x8*)(kt[cur] + (jsub * 16 + c16) * 32 + ((g ^ swq) * 8));
            f32x4 z = {0.f, 0.f, 0.f, 0.f};
            sacc[jsub] = __builtin_amdgcn_mfma_f32_16x16x32_bf16(kfrag, qfrag, z, 0, 0, 0);
        }
        // ---- mask + per-lane online softmax (row i lane-local) ----
        float mx = NEG_BIG;
        #pragma unroll
        for (int jsub = 0; jsub < 8; ++jsub) {
            int wsel = jsub >> 1;
            unsigned mw = wsel == 0 ? am.x : wsel == 1 ? am.y : wsel == 2 ? am.z : am.w;
            #pragma unroll
            for (int r = 0; r < 4; ++r) {
                bool alive = (mw >> ((jsub & 1) * 16 + g * 4 + r)) & 1u;
                float s = alive ? sacc[jsub][r] : NEG_BIG;
                sacc[jsub][r] = s;
                mx = fmaxf(mx, s);
            }
        }
        mx = fmaxf(mx, __shfl_xor(mx, 16));
        mx = fmaxf(mx, __shfl_xor(mx, 32));
        float mnew = fmaxf(mrun, mx);
        float sf = __expf(mrun - mnew);
        mrun = mnew;
        float rs = 0.0f;
        #pragma unroll
        for (int jsub = 0; jsub < 8; ++jsub)
            #pragma unroll
            for (int r = 0; r < 4; ++r) {
                float pv = (sacc[jsub][r] > -0.9e30f) ? __expf(sacc[jsub][r] - mnew) : 0.0f;
                sacc[jsub][r] = pv;
                rs += pv;
            }
        rs += __shfl_xor(rs, 16);
        rs += __shfl_xor(rs, 32);
        lrun = lrun * sf + rs;
        // ---- pack P (cvt_pk) -> per-wave LDS, 8 x b64 ----
        #pragma unroll
        for (int jsub = 0; jsub < 8; ++jsub) {
            unsigned lo, hi;
            asm("v_cvt_pk_bf16_f32 %0, %1, %2" : "=v"(lo) : "v"(sacc[jsub][0]), "v"(sacc[jsub][1]));
            asm("v_cvt_pk_bf16_f32 %0, %1, %2" : "=v"(hi) : "v"(sacc[jsub][2]), "v"(sacc[jsub][3]));
            uint2 pk2; pk2.x = lo; pk2.y = hi;
            *(uint2*)(&pl[w][c16 * 136 + jsub * 16 + g * 4]) = pk2;
        }
        // rescale O (sf lane-local) while P writes land
        #pragma unroll
        for (int dsub = 0; dsub < 2; ++dsub)
            #pragma unroll
            for (int r = 0; r < 4; ++r)
                oacc[dsub][r] *= sf;
        asm volatile("s_waitcnt lgkmcnt(0)" ::: "memory");
        // ---- O^T += V^T P : 4 ks x 2 dsub ----
        #pragma unroll
        for (int ks = 0; ks < 4; ++ks) {
            bf16x8 pa = *(const bf16x8*)(&pl[w][c16 * 136 + ks * 32 + g * 8]);
            #pragma unroll
            for (int dsub = 0; dsub < 2; ++dsub) {
                int cj = ks * 4 + g;
                bf16x8 va = *(const bf16x8*)(vt[cur] + (dsub * 16 + c16) * 128 +
                                             (cj >> 3) * 64 + (((cj & 7) ^ (c16 & 7)) * 8));
                oacc[dsub] = __builtin_amdgcn_mfma_f32_16x16x32_bf16(va, pa, oacc[dsub], 0, 0, 0);
            }
        }
        if (jt < 7) {
            am = amn;
            __syncthreads();
        }
    }
    // ---- epilogue ----
    float inv = (lrun > 0.0f) ? (1.0f / lrun) : 0.0f;
    #pragma unroll
    for (int dsub = 0; dsub < 2; ++dsub) {
        float4 o;
        o.x = oacc[dsub][0] * inv; o.y = oacc[dsub][1] * inv;
        o.z = oacc[dsub][2] * inv; o.w = oacc[dsub][3] * inv;
        *(float4*)(ao + ((size_t)(b * N + i0 + w * 16 + c16)) * H +
                   head * HD + dsub * 16 + g * 4) = o;
    }
}

// ---- split fp32 tile -> bf16 hi/lo LDS (stride 130), activations only ----
__device__ __forceinline__ void stage_split(
    const float* __restrict__ src, unsigned short* hi, unsigned short* lo, int t) {
    #pragma unroll
    for (int it = 0; it < 8; ++it) {
        int idx4 = it * 256 + t;
        int row = idx4 >> 5, c4 = (idx4 & 31) * 4;
        float4 f = ((const float4*)src)[idx4];
        unsigned short h0 = f2bf(f.x), h1 = f2bf(f.y), h2 = f2bf(f.z), h3 = f2bf(f.w);
        unsigned short l0 = f2bf(f.x - bf2f(h0)), l1 = f2bf(f.y - bf2f(h1));
        unsigned short l2 = f2bf(f.z - bf2f(h2)), l3 = f2bf(f.w - bf2f(h3));
        *(unsigned*)(hi + row * 130 + c4)     = (unsigned)h0 | ((unsigned)h1 << 16);
        *(unsigned*)(hi + row * 130 + c4 + 2) = (unsigned)h2 | ((unsigned)h3 << 16);
        *(unsigned*)(lo + row * 130 + c4)     = (unsigned)l0 | ((unsigned)l1 << 16);
        *(unsigned*)(lo + row * 130 + c4 + 2) = (unsigned)l2 | ((unsigned)l3 << 16);
    }
}

// ---- 3-term split GEMM core ----
__device__ __forceinline__ void split_gemm(
    const unsigned short* ah, const unsigned short* al,
    const unsigned short* wh, const unsigned short* wl,
    int arow, int g, int c16, f32x4* acc) {
    bf16x8 ahf[4], alf[4];
    #pragma unroll
    for (int ks = 0; ks < 4; ++ks) {
        ahf[ks] = *(const bf16x8*)(ah + arow * 130 + ks * 32 + g * 8);
        alf[ks] = *(const bf16x8*)(al + arow * 130 + ks * 32 + g * 8);
    }
    #pragma unroll
    for (int sub = 0; sub < 8; ++sub) {
        int bcol = sub * 16 + c16;
        f32x4 z = {0.f, 0.f, 0.f, 0.f};
        #pragma unroll
        for (int ks = 0; ks < 4; ++ks) {
            bf16x8 bh = *(const bf16x8*)(wh + bcol * 128 + (((ks * 4 + g) ^ (bcol & 7)) * 8));
            bf16x8 bl = *(const bf16x8*)(wl + bcol * 128 + (((ks * 4 + g) ^ (bcol & 7)) * 8));
            z = __builtin_amdgcn_mfma_f32_16x16x32_bf16(ahf[ks], bh, z, 0, 0, 0);
            z = __builtin_amdgcn_mfma_f32_16x16x32_bf16(alf[ks], bh, z, 0, 0, 0);
            z = __builtin_amdgcn_mfma_f32_16x16x32_bf16(ahf[ks], bl, z, 0, 0, 0);
        }
        acc[sub] = z;
    }
}

__device__ __forceinline__ void stage_w(const unsigned short* __restrict__ src,
                                        unsigned short* dst, int t, int w) {
    #pragma unroll
    for (int i = 0; i < 8; ++i) {
        int ci = i * 256 + t, row = ci >> 4, cr = ci & 15;
        gload_lds16(src + (size_t)row * 128 + (cr ^ (row & 7)) * 8,
                    (char*)dst + (i * 4 + w) * 1024);
    }
}

// ------- layer-0: O-proj + LN + relu + residual -------
__global__ __launch_bounds__(256) void oln_kernel(
    const float* __restrict__ ao, const unsigned short* __restrict__ woh_l,
    const unsigned short* __restrict__ wol_l, const float* __restrict__ ob,
    const float* __restrict__ lng, const float* __restrict__ lnb,
    float* __restrict__ h, unsigned short* __restrict__ h_bf) {
    __shared__ unsigned short ah[64 * 130], al[64 * 130];
    __shared__ unsigned short wh[128 * 128], wl[128 * 128];
    const int t = threadIdx.x;
    const int r0 = blockIdx.x * 64;
    const int w = t >> 6, lane = t & 63, g = lane >> 4, c16 = lane & 15;

    stage_w(woh_l, wh, t, w);
    stage_w(wol_l, wl, t, w);
    stage_split(ao + (size_t)r0 * H, ah, al, t);
    __syncthreads();

    const int arow = w * 16 + c16;
    f32x4 acc[8];
    split_gemm(ah, al, wh, wl, arow, g, c16, acc);

    float val[8][4], s1[4] = {0, 0, 0, 0}, s2[4] = {0, 0, 0, 0};
    #pragma unroll
    for (int sub = 0; sub < 8; ++sub) {
        int col = sub * 16 + c16;
        float bias = ob[col];
        #pragma unroll
        for (int rr = 0; rr < 4; ++rr) {
            float vv = acc[sub][rr] + bias;
            val[sub][rr] = vv;
            s1[rr] += vv;
            s2[rr] += vv * vv;
        }
    }
    #pragma unroll
    for (int rr = 0; rr < 4; ++rr) {
        #pragma unroll
        for (int off = 1; off < 16; off <<= 1) {
            s1[rr] += __shfl_xor(s1[rr], off);
            s2[rr] += __shfl_xor(s2[rr], off);
        }
    }
    #pragma unroll
    for (int rr = 0; rr < 4; ++rr) {
        float mu = s1[rr] * (1.0f / H);
        float var = s2[rr] * (1.0f / H) - mu * mu;
        float rsn = rsqrtf(var + EPS);
        int row = r0 + w * 16 + g * 4 + rr;
        #pragma unroll
        for (int sub = 0; sub < 8; ++sub) {
            int col = sub * 16 + c16;
            float y = (val[sub][rr] - mu) * rsn * lng[col] + lnb[col];
            float hn = fmaxf(y, 0.0f) + h[(size_t)row * H + col];
            h[(size_t)row * H + col] = hn;
            h_bf[(size_t)row * H + col] = f2bf(hn);
        }
    }
}

// ------- layer-1 fused: O-proj + LN + relu + residual + final proj -> out -------
__global__ __launch_bounds__(256) void olnfinal_kernel(
    const float* __restrict__ ao, const unsigned short* __restrict__ woh_l,
    const unsigned short* __restrict__ wol_l, const float* __restrict__ ob,
    const float* __restrict__ lng, const float* __restrict__ lnb,
    const float* __restrict__ h, const unsigned short* __restrict__ wfh,
    const unsigned short* __restrict__ wfl, const float* __restrict__ fb,
    float* __restrict__ out) {
    __shared__ unsigned short ah[64 * 130], al[64 * 130];
    __shared__ unsigned short wh[128 * 128], wl[128 * 128];
    const int t = threadIdx.x;
    const int r0 = blockIdx.x * 64;
    const int w = t >> 6, lane = t & 63, g = lane >> 4, c16 = lane & 15;

    stage_w(woh_l, wh, t, w);
    stage_w(wol_l, wl, t, w);
    stage_split(ao + (size_t)r0 * H, ah, al, t);
    __syncthreads();

    const int arow = w * 16 + c16;
    f32x4 acc[8];
    split_gemm(ah, al, wh, wl, arow, g, c16, acc);

    float val[8][4], s1[4] = {0, 0, 0, 0}, s2[4] = {0, 0, 0, 0};
    #pragma unroll
    for (int sub = 0; sub < 8; ++sub) {
        int col = sub * 16 + c16;
        float bias = ob[col];
        #pragma unroll
        for (int rr = 0; rr < 4; ++rr) {
            float vv = acc[sub][rr] + bias;
            val[sub][rr] = vv;
            s1[rr] += vv;
            s2[rr] += vv * vv;
        }
    }
    #pragma unroll
    for (int rr = 0; rr < 4; ++rr) {
        #pragma unroll
        for (int off = 1; off < 16; off <<= 1) {
            s1[rr] += __shfl_xor(s1[rr], off);
            s2[rr] += __shfl_xor(s2[rr], off);
        }
    }
    __syncthreads();
    #pragma unroll
    for (int rr = 0; rr < 4; ++rr) {
        float mu = s1[rr] * (1.0f / H);
        float var = s2[rr] * (1.0f / H) - mu * mu;
        float rsn = rsqrtf(var + EPS);
        int row = w * 16 + g * 4 + rr;
        #pragma unroll
        for (int sub = 0; sub < 8; ++sub) {
            int col = sub * 16 + c16;
            float y = (val[sub][rr] - mu) * rsn * lng[col] + lnb[col];
            float hn = fmaxf(y, 0.0f) + h[(size_t)(r0 + row) * H + col];
            unsigned short hi = f2bf(hn);
            ah[row * 130 + col] = hi;
            al[row * 130 + col] = f2bf(hn - bf2f(hi));
        }
    }
    stage_w(wfh, wh, t, w);
    stage_w(wfl, wl, t, w);
    __syncthreads();

    f32x4 fac[8];
    split_gemm(ah, al, wh, wl, arow, g, c16, fac);
    #pragma unroll
    for (int sub = 0; sub < 8; ++sub) {
        int col = sub * 16 + c16;
        float bias = fb[col];
        #pragma unroll
        for (int rr = 0; rr < 4; ++rr) {
            int row = r0 + w * 16 + g * 4 + rr;
            out[(size_t)row * H + col] = fac[sub][rr] + bias;
        }
    }
}

extern "C" void kernel_launch(void* const* d_in, const int* in_sizes, int n_in,
                              void* d_out, int out_size, void* d_ws, size_t ws_size,
                              hipStream_t stream) {
    const float* x     = (const float*)d_in[0];
    const float* adj   = (const float*)d_in[1];
    const float* enc_w = (const float*)d_in[2];
    const float* enc_b = (const float*)d_in[3];
    const float* q_w   = (const float*)d_in[4];
    const float* q_b   = (const float*)d_in[5];
    const float* k_w   = (const float*)d_in[6];
    const float* k_b   = (const float*)d_in[7];
    const float* v_w   = (const float*)d_in[8];
    const float* v_b   = (const float*)d_in[9];
    const float* o_w   = (const float*)d_in[10];
    const float* o_b   = (const float*)d_in[11];
    const float* ln_g  = (const float*)d_in[12];
    const float* ln_b  = (const float*)d_in[13];
    const float* out_w = (const float*)d_in[14];
    const float* out_b = (const float*)d_in[15];

    const size_t BNH = (size_t)B * N * H;
    float* h  = (float*)d_ws;
    float* ao = h + BNH;
    unsigned short* h_bf = (unsigned short*)(ao + BNH);
    unsigned short* qb = h_bf + BNH;
    unsigned short* kb = qb + BNH;
    unsigned short* vT = kb + BNH;
    unsigned* mbits = (unsigned*)(vT + BNH);
    unsigned short* x_bf = (unsigned short*)(mbits + (size_t)B * N * N / 32);
    unsigned short* wenc = x_bf + (size_t)B * N * D_IN;
    unsigned short* wqkv = wenc + H * D_IN;
    float* bqkv = (float*)(wqkv + (size_t)L * 3 * H * H);
    unsigned short* woh = (unsigned short*)(bqkv + L * 3 * H);
    unsigned short* wol = woh + (size_t)L * H * H;
    unsigned short* wfh = wol + (size_t)L * H * H;
    unsigned short* wfl = wfh + (size_t)H * H;

    pack_kernel<<<B * N * N / 32 / 256, 256, 0, stream>>>(adj, mbits);
    const int prep_total = B * N * D_IN + H * D_IN + L * 3 * H * H + L * 3 * H
                         + L * H * H + H * H;
    prep_kernel<<<(prep_total + 255) / 256, 256, 0, stream>>>(
        x, enc_w, q_w, k_w, v_w, q_b, k_b, v_b, o_w, out_w,
        x_bf, wenc, wqkv, bqkv, woh, wol, wfh, wfl);
    enc_kernel<<<B * N / 64, 256, 0, stream>>>(x_bf, wenc, enc_b, h, h_bf);

    // layer 0
    qkv_kernel<<<B * N / 32, 256, 0, stream>>>(h_bf, wqkv, bqkv, qb, kb, vT);
    attn_kernel<<<B * HEADS * (N / 64), 256, 0, stream>>>(qb, kb, vT, mbits, ao);
    oln_kernel<<<B * N / 64, 256, 0, stream>>>(
        ao, woh, wol, o_b, ln_g, ln_b, h, h_bf);
    // layer 1 (+ final fused)
    qkv_kernel<<<B * N / 32, 256, 0, stream>>>(
        h_bf, wqkv + (size_t)3 * H * H, bqkv + 3 * H, qb, kb, vT);
    attn_kernel<<<B * HEADS * (N / 64), 256, 0, stream>>>(qb, kb, vT, mbits, ao);
    olnfinal_kernel<<<B * N / 64, 256, 0, stream>>>(
        ao, woh + (size_t)H * H, wol + (size_t)H * H, o_b + H,
        ln_g + H, ln_b + H, h, wfh, wfl, out_b, (float*)d_out);
}